// Round 1
// baseline (565.692 us; speedup 1.0000x reference)
//
#include <hip/hip_runtime.h>

// ---------------- problem constants ----------------
#define NNODES 50000
#define INC 100
#define HIDC 128
#define OUTC 40

// ---------------- CSR build ----------------
__global__ __launch_bounds__(256) void count_kernel(const int* __restrict__ dst,
                                                    int* __restrict__ deg, int E) {
    int e = blockIdx.x * 256 + threadIdx.x;
    if (e < E) atomicAdd(&deg[dst[e]], 1);
}

// single-block exclusive scan (Hillis-Steele per 1024-chunk + running carry)
__global__ __launch_bounds__(1024) void scan_kernel(const int* __restrict__ deg,
                                                    int* __restrict__ offs,
                                                    int* __restrict__ cursor, int n) {
    __shared__ int temp[1024];
    __shared__ int s_carry;
    if (threadIdx.x == 0) s_carry = 0;
    __syncthreads();
    for (int base = 0; base < n; base += 1024) {
        int i = base + (int)threadIdx.x;
        int v = (i < n) ? deg[i] : 0;
        temp[threadIdx.x] = v;
        __syncthreads();
        for (int off = 1; off < 1024; off <<= 1) {
            int t = (threadIdx.x >= off) ? temp[threadIdx.x - off] : 0;
            __syncthreads();
            temp[threadIdx.x] += t;
            __syncthreads();
        }
        int incl = temp[threadIdx.x];
        int carry = s_carry;
        if (i < n) {
            int excl = carry + incl - v;
            offs[i] = excl;
            cursor[i] = excl;
        }
        __syncthreads();
        if (threadIdx.x == 1023) s_carry = carry + temp[1023];
        __syncthreads();
    }
    if (threadIdx.x == 0) offs[n] = s_carry;
}

__global__ __launch_bounds__(256) void scatter_kernel(const int* __restrict__ src,
                                                      const int* __restrict__ dst,
                                                      int* __restrict__ cursor,
                                                      int* __restrict__ csr_src, int E) {
    int e = blockIdx.x * 256 + threadIdx.x;
    if (e < E) {
        int pos = atomicAdd(&cursor[dst[e]], 1);
        csr_src[pos] = src[e];
    }
}

// ---------------- GIN aggregation: out[n] = feat[n] + sum_{j in N(n)} feat[j] ----------------
template <int C>
__global__ __launch_bounds__(128) void agg_kernel(const float* __restrict__ feat,
                                                  const int* __restrict__ offs,
                                                  const int* __restrict__ csr_src,
                                                  float* __restrict__ out, int N) {
    int node = blockIdx.x;
    int c = threadIdx.x;
    if (node >= N || c >= C) return;
    int s = offs[node], e = offs[node + 1];
    float acc = feat[(size_t)node * C + c];
    for (int i = s; i < e; ++i) {
        int sn = csr_src[i];
        acc += feat[(size_t)sn * C + c];
    }
    out[(size_t)node * C + c] = acc;
}

// ---------------- fused GEMM + bias (+ReLU): out[N,J] = act(A[N,K] @ W[K,J] + b) ----------------
// 256 threads, NT nodes per block. A tile staged in LDS (broadcast reads).
template <int K, int J, int NT, bool RELU>
__global__ __launch_bounds__(256) void mlp_gemm(const float* __restrict__ A,
                                                const float* __restrict__ W,
                                                const float* __restrict__ bias,
                                                float* __restrict__ out, int N) {
    constexpr int JL = (J > 64) ? J : 64;        // lanes per j-group (pad 40 -> 64)
    constexpr int GROUPS = 256 / JL;             // 2 (J=128) or 4 (J<=64)
    constexpr int NPT = NT / GROUPS;             // nodes per thread
    __shared__ float As[NT][K + 1];

    int n0 = blockIdx.x * NT;
    for (int idx = threadIdx.x; idx < NT * K; idx += 256) {
        int r = idx / K, c = idx - r * K;
        int n = n0 + r;
        As[r][c] = (n < N) ? A[(size_t)n * K + c] : 0.f;
    }
    __syncthreads();

    int j = threadIdx.x % JL;
    int g = threadIdx.x / JL;

    float acc[NPT];
    float b = (j < J) ? bias[j] : 0.f;
#pragma unroll
    for (int i = 0; i < NPT; ++i) acc[i] = b;

    if (j < J) {
        for (int k = 0; k < K; ++k) {
            float w = W[k * J + j];
#pragma unroll
            for (int i = 0; i < NPT; ++i)
                acc[i] += As[g + i * GROUPS][k] * w;
        }
#pragma unroll
        for (int i = 0; i < NPT; ++i) {
            int n = n0 + g + i * GROUPS;
            if (n < N) {
                float v = acc[i];
                if (RELU) v = fmaxf(v, 0.f);
                out[(size_t)n * J + j] = v;
            }
        }
    }
}

// ---------------- final: logits = T[N,40] @ W2b[40,40] + b2b ; out = log_softmax(logits) ----------------
// one 64-lane wave per node, 4 nodes per 256-thread block
__global__ __launch_bounds__(256) void mlp2b_lsm(const float* __restrict__ T,
                                                 const float* __restrict__ W,
                                                 const float* __restrict__ bias,
                                                 float* __restrict__ out, int N) {
    __shared__ float Ws[OUTC * OUTC];
    __shared__ float bs[OUTC];
    for (int i = threadIdx.x; i < OUTC * OUTC; i += 256) Ws[i] = W[i];
    if (threadIdx.x < OUTC) bs[threadIdx.x] = bias[threadIdx.x];
    __syncthreads();

    int wave = threadIdx.x >> 6;
    int lane = threadIdx.x & 63;
    int n = blockIdx.x * 4 + wave;
    if (n >= N) return;

    const float* trow = T + (size_t)n * OUTC;
    float logit = -INFINITY;
    if (lane < OUTC) {
        float a = bs[lane];
        for (int k = 0; k < OUTC; ++k) a += trow[k] * Ws[k * OUTC + lane];
        logit = a;
    }
    float m = logit;
#pragma unroll
    for (int off = 32; off; off >>= 1) m = fmaxf(m, __shfl_xor(m, off));
    float ex = (lane < OUTC) ? expf(logit - m) : 0.f;
    float s = ex;
#pragma unroll
    for (int off = 32; off; off >>= 1) s += __shfl_xor(s, off);
    if (lane < OUTC) out[(size_t)n * OUTC + lane] = logit - m - logf(s);
}

// ---------------- launcher ----------------
extern "C" void kernel_launch(void* const* d_in, const int* in_sizes, int n_in,
                              void* d_out, int out_size, void* d_ws, size_t ws_size,
                              hipStream_t stream) {
    const float* x   = (const float*)d_in[0];
    const int* edges = (const int*)d_in[1];
    const float* W1a = (const float*)d_in[2];
    const float* b1a = (const float*)d_in[3];
    const float* W1b = (const float*)d_in[4];
    const float* b1b = (const float*)d_in[5];
    const float* W2a = (const float*)d_in[6];
    const float* b2a = (const float*)d_in[7];
    const float* W2b = (const float*)d_in[8];
    const float* b2b = (const float*)d_in[9];

    const int N = NNODES;
    const int E = in_sizes[1] / 2;
    const int* srcp = edges;
    const int* dstp = edges + E;

    // workspace carve-out (256B aligned)
    auto au = [](size_t v) { return (v + 255) & ~(size_t)255; };
    char* p = (char*)d_ws;
    int* deg    = (int*)p; p += au((size_t)N * 4);
    int* offs   = (int*)p; p += au((size_t)(N + 1) * 4);
    int* cursor = (int*)p; p += au((size_t)N * 4);
    int* csr    = (int*)p; p += au((size_t)E * 4);
    float* bufA = (float*)p; p += au((size_t)N * INC * 4);   // agg1 out, later T2 (N x 40)
    float* bufB = (float*)p; p += au((size_t)N * HIDC * 4);  // X1, later agg2 out
    float* bufC = (float*)p; p += au((size_t)N * HIDC * 4);  // H1

    // ---- CSR build (once per call, reused by both aggregations)
    hipMemsetAsync(deg, 0, (size_t)N * sizeof(int), stream);
    count_kernel<<<(E + 255) / 256, 256, 0, stream>>>(dstp, deg, E);
    scan_kernel<<<1, 1024, 0, stream>>>(deg, offs, cursor, N);
    scatter_kernel<<<(E + 255) / 256, 256, 0, stream>>>(srcp, dstp, cursor, csr, E);

    // ---- layer 1
    agg_kernel<INC><<<N, 128, 0, stream>>>(x, offs, csr, bufA, N);
    mlp_gemm<INC, HIDC, 64, true><<<(N + 63) / 64, 256, 0, stream>>>(bufA, W1a, b1a, bufB, N);
    mlp_gemm<HIDC, HIDC, 64, true><<<(N + 63) / 64, 256, 0, stream>>>(bufB, W1b, b1b, bufC, N);

    // ---- layer 2
    agg_kernel<HIDC><<<N, 128, 0, stream>>>(bufC, offs, csr, bufB, N);
    mlp_gemm<HIDC, OUTC, 64, true><<<(N + 63) / 64, 256, 0, stream>>>(bufB, W2a, b2a, bufA, N);
    mlp2b_lsm<<<(N + 3) / 4, 256, 0, stream>>>(bufA, W2b, b2b, (float*)d_out, N);
}

// Round 2
// 335.763 us; speedup vs baseline: 1.6848x; 1.6848x over previous
//
#include <hip/hip_runtime.h>

// ---------------- problem constants ----------------
#define NNODES 50000
#define INC 100
#define HIDC 128
#define OUTC 40

// ================= CSR build =================
__global__ __launch_bounds__(256) void count_kernel(const int* __restrict__ dst,
                                                    int* __restrict__ deg, int E) {
    int e = blockIdx.x * 256 + threadIdx.x;
    if (e < E) atomicAdd(&deg[dst[e]], 1);
}

// pass 1: per-1024-chunk exclusive scan (256 thr x 4 elems), emit chunk sums
__global__ __launch_bounds__(256) void scan_pass1(const int* __restrict__ deg,
                                                  int* __restrict__ lexcl,
                                                  int* __restrict__ blk_sums, int n) {
    __shared__ int wsum[4];
    int base = blockIdx.x * 1024;
    int t = threadIdx.x;
    int i0 = base + t * 4;
    int a = (i0 + 0 < n) ? deg[i0 + 0] : 0;
    int b = (i0 + 1 < n) ? deg[i0 + 1] : 0;
    int c = (i0 + 2 < n) ? deg[i0 + 2] : 0;
    int d = (i0 + 3 < n) ? deg[i0 + 3] : 0;
    int s4 = a + b + c + d;
    int lane = t & 63, w = t >> 6;
    int incl = s4;
#pragma unroll
    for (int off = 1; off < 64; off <<= 1) {
        int u = __shfl_up(incl, off);
        if (lane >= off) incl += u;
    }
    if (lane == 63) wsum[w] = incl;
    __syncthreads();
    int wbase = 0;
#pragma unroll
    for (int j = 0; j < 4; ++j)
        if (j < w) wbase += wsum[j];
    int excl = wbase + incl - s4;
    if (i0 + 0 < n) lexcl[i0 + 0] = excl;
    if (i0 + 1 < n) lexcl[i0 + 1] = excl + a;
    if (i0 + 2 < n) lexcl[i0 + 2] = excl + a + b;
    if (i0 + 3 < n) lexcl[i0 + 3] = excl + a + b + c;
    if (t == 255) blk_sums[blockIdx.x] = wbase + incl;
}

// pass 2: scan block sums (<=64 blocks), convert to exclusive bases, total -> offs[n]
__global__ __launch_bounds__(64) void scan_pass2(int* __restrict__ blk_sums, int nb,
                                                 int* __restrict__ offs_end) {
    int lane = threadIdx.x;
    int v = (lane < nb) ? blk_sums[lane] : 0;
    int incl = v;
#pragma unroll
    for (int off = 1; off < 64; off <<= 1) {
        int u = __shfl_up(incl, off);
        if (lane >= off) incl += u;
    }
    if (lane < nb) blk_sums[lane] = incl - v;
    if (lane == 63) offs_end[0] = incl;
}

// pass 3: add block base, emit offs + cursor
__global__ __launch_bounds__(256) void scan_pass3(const int* __restrict__ lexcl,
                                                  const int* __restrict__ blk_sums,
                                                  int* __restrict__ offs,
                                                  int* __restrict__ cursor, int n) {
    int i = blockIdx.x * 256 + threadIdx.x;
    if (i < n) {
        int v = lexcl[i] + blk_sums[i >> 10];
        offs[i] = v;
        cursor[i] = v;
    }
}

__global__ __launch_bounds__(256) void scatter_kernel(const int* __restrict__ src,
                                                      const int* __restrict__ dst,
                                                      int* __restrict__ cursor,
                                                      int* __restrict__ csr_src, int E) {
    int e = blockIdx.x * 256 + threadIdx.x;
    if (e < E) {
        int pos = atomicAdd(&cursor[dst[e]], 1);
        csr_src[pos] = src[e];
    }
}

// ================= GIN aggregation (float4, 32 lanes/node, 8 nodes/block) =================
template <int C4>
__global__ __launch_bounds__(256) void agg_v2(const float4* __restrict__ feat,
                                              const int* __restrict__ offs,
                                              const int* __restrict__ csr,
                                              float4* __restrict__ out, int N) {
    int node = blockIdx.x * 8 + (threadIdx.x >> 5);
    int l = threadIdx.x & 31;
    if (node >= N || l >= C4) return;
    int s = offs[node], e = offs[node + 1];
    float4 acc = feat[(size_t)node * C4 + l];
    for (int i = s; i < e; ++i) {
        int sn = csr[i];
        float4 v = feat[(size_t)sn * C4 + l];
        acc.x += v.x; acc.y += v.y; acc.z += v.z; acc.w += v.w;
    }
    out[(size_t)node * C4 + l] = acc;
}

// ================= register-tiled GEMM: out[N,128] = act(A[N,K] @ W[K,128] + b) =================
// 256 threads = 16 (j-groups) x 16 (node-groups); thread tile 4 nodes x 8 cols.
template <int K, int KC, bool RELU>
__global__ __launch_bounds__(256) void gemm128_v2(const float* __restrict__ A,
                                                  const float* __restrict__ W,
                                                  const float* __restrict__ bias,
                                                  float* __restrict__ out, int N) {
    constexpr int J = 128;
    constexpr int BM = 64;
    constexpr int LDA = K + 4;  // padded stride (floats); (K+4)*4 bytes stays 16B-aligned
    __shared__ float As[BM * LDA];
    __shared__ float Wc[KC * J];

    const int tid = threadIdx.x;
    const int n0 = blockIdx.x * BM;

    // stage A tile (float4 loads, zero-pad OOB rows)
    constexpr int K4 = K / 4;
    for (int idx = tid; idx < BM * K4; idx += 256) {
        int r = idx / K4, c4 = idx - r * K4;
        int n = n0 + r;
        float4 v = make_float4(0.f, 0.f, 0.f, 0.f);
        if (n < N) v = reinterpret_cast<const float4*>(A + (size_t)n * K)[c4];
        *reinterpret_cast<float4*>(&As[r * LDA + c4 * 4]) = v;
    }

    const int tx = tid & 15;
    const int ty = tid >> 4;
    const int jb = tx * 8;
    const int r0 = (ty + 0) * LDA;
    const int r1 = (ty + 16) * LDA;
    const int r2 = (ty + 32) * LDA;
    const int r3 = (ty + 48) * LDA;

    float acc[4][8];
    {
        float4 b0 = *reinterpret_cast<const float4*>(&bias[jb]);
        float4 b1 = *reinterpret_cast<const float4*>(&bias[jb + 4]);
        float bb[8] = {b0.x, b0.y, b0.z, b0.w, b1.x, b1.y, b1.z, b1.w};
#pragma unroll
        for (int i = 0; i < 4; ++i)
#pragma unroll
            for (int m = 0; m < 8; ++m) acc[i][m] = bb[m];
    }

    for (int kb = 0; kb < K; kb += KC) {
        __syncthreads();  // A ready (iter 0) / Wc consumed (later iters)
        // stage W chunk rows [kb, kb+KC)
        for (int idx = tid; idx < KC * (J / 4); idx += 256) {
            int r = idx >> 5, c4 = idx & 31;
            *reinterpret_cast<float4*>(&Wc[r * J + c4 * 4]) =
                *reinterpret_cast<const float4*>(&W[(size_t)(kb + r) * J + c4 * 4]);
        }
        __syncthreads();
#pragma unroll
        for (int k = 0; k < KC; ++k) {
            float a[4];
            a[0] = As[r0 + kb + k];
            a[1] = As[r1 + kb + k];
            a[2] = As[r2 + kb + k];
            a[3] = As[r3 + kb + k];
            float4 w0 = *reinterpret_cast<const float4*>(&Wc[k * J + jb]);
            float4 w1 = *reinterpret_cast<const float4*>(&Wc[k * J + jb + 4]);
            float w[8] = {w0.x, w0.y, w0.z, w0.w, w1.x, w1.y, w1.z, w1.w};
#pragma unroll
            for (int i = 0; i < 4; ++i)
#pragma unroll
                for (int m = 0; m < 8; ++m) acc[i][m] = fmaf(a[i], w[m], acc[i][m]);
        }
    }

    const int rows[4] = {ty, ty + 16, ty + 32, ty + 48};
#pragma unroll
    for (int i = 0; i < 4; ++i) {
        int n = n0 + rows[i];
        if (n < N) {
            float o[8];
#pragma unroll
            for (int m = 0; m < 8; ++m) o[m] = RELU ? fmaxf(acc[i][m], 0.f) : acc[i][m];
            *reinterpret_cast<float4*>(&out[(size_t)n * J + jb]) =
                make_float4(o[0], o[1], o[2], o[3]);
            *reinterpret_cast<float4*>(&out[(size_t)n * J + jb + 4]) =
                make_float4(o[4], o[5], o[6], o[7]);
        }
    }
}

// ================= fused: relu(Ag@W2a+b2a) @ W2b + b2b -> log_softmax =================
// 256 threads = 8 (j-groups of 5) x 32 (node-groups); BM=64, thread tile 2 nodes x 5 cols.
__global__ __launch_bounds__(256) void mlp2_fused(const float* __restrict__ Ag,
                                                  const float* __restrict__ W2a,
                                                  const float* __restrict__ b2a,
                                                  const float* __restrict__ W2b,
                                                  const float* __restrict__ b2b,
                                                  float* __restrict__ out, int N) {
    constexpr int K = 128, H = 40, BM = 64;
    constexpr int LDA = K + 4;   // 132
    constexpr int LDW = 44;
    __shared__ float As[BM * LDA];   // 33.8 KB
    __shared__ float Ws1[K * LDW];   // 22.5 KB
    __shared__ float Ws2[H * LDW];   // 7.0 KB
    __shared__ float Ts[BM * LDW];   // 11.3 KB
    __shared__ float bs2[H];

    const int tid = threadIdx.x;
    const int n0 = blockIdx.x * BM;

    for (int idx = tid; idx < BM * (K / 4); idx += 256) {
        int r = idx >> 5, c4 = idx & 31;
        int n = n0 + r;
        float4 v = make_float4(0.f, 0.f, 0.f, 0.f);
        if (n < N) v = reinterpret_cast<const float4*>(Ag + (size_t)n * K)[c4];
        *reinterpret_cast<float4*>(&As[r * LDA + c4 * 4]) = v;
    }
    for (int idx = tid; idx < K * (H / 4); idx += 256) {
        int r = idx / 10, c4 = idx - r * 10;
        *reinterpret_cast<float4*>(&Ws1[r * LDW + c4 * 4]) =
            *reinterpret_cast<const float4*>(&W2a[r * H + c4 * 4]);
    }
    for (int idx = tid; idx < H * (H / 4); idx += 256) {
        int r = idx / 10, c4 = idx - r * 10;
        *reinterpret_cast<float4*>(&Ws2[r * LDW + c4 * 4]) =
            *reinterpret_cast<const float4*>(&W2b[r * H + c4 * 4]);
    }
    if (tid < H) bs2[tid] = b2b[tid];
    __syncthreads();

    const int tx = tid & 7;
    const int ty = tid >> 3;  // 0..31
    const int jb = tx * 5;

    // phase 1: t = relu(Ag @ W2a + b2a)
    float acc[2][5];
#pragma unroll
    for (int m = 0; m < 5; ++m) {
        float b = b2a[jb + m];
        acc[0][m] = b;
        acc[1][m] = b;
    }
    const int r0 = ty * LDA, r1 = (ty + 32) * LDA;
#pragma unroll 8
    for (int k = 0; k < K; ++k) {
        float a0 = As[r0 + k];
        float a1 = As[r1 + k];
#pragma unroll
        for (int m = 0; m < 5; ++m) {
            float w = Ws1[k * LDW + jb + m];
            acc[0][m] = fmaf(a0, w, acc[0][m]);
            acc[1][m] = fmaf(a1, w, acc[1][m]);
        }
    }
#pragma unroll
    for (int m = 0; m < 5; ++m) {
        Ts[ty * LDW + jb + m] = fmaxf(acc[0][m], 0.f);
        Ts[(ty + 32) * LDW + jb + m] = fmaxf(acc[1][m], 0.f);
    }
    __syncthreads();

    // phase 2: logits = t @ W2b + b2b
    float lg[2][5];
#pragma unroll
    for (int m = 0; m < 5; ++m) {
        float b = bs2[jb + m];
        lg[0][m] = b;
        lg[1][m] = b;
    }
#pragma unroll 8
    for (int q = 0; q < H; ++q) {
        float t0 = Ts[ty * LDW + q];
        float t1 = Ts[(ty + 32) * LDW + q];
#pragma unroll
        for (int m = 0; m < 5; ++m) {
            float w = Ws2[q * LDW + jb + m];
            lg[0][m] = fmaf(t0, w, lg[0][m]);
            lg[1][m] = fmaf(t1, w, lg[1][m]);
        }
    }

    // log_softmax: reduce across the 8 tx lanes (lane bits 0..2)
#pragma unroll
    for (int i = 0; i < 2; ++i) {
        float m5 = lg[i][0];
#pragma unroll
        for (int m = 1; m < 5; ++m) m5 = fmaxf(m5, lg[i][m]);
#pragma unroll
        for (int off = 1; off < 8; off <<= 1) m5 = fmaxf(m5, __shfl_xor(m5, off));
        float s5 = 0.f;
#pragma unroll
        for (int m = 0; m < 5; ++m) s5 += expf(lg[i][m] - m5);
#pragma unroll
        for (int off = 1; off < 8; off <<= 1) s5 += __shfl_xor(s5, off);
        float lse = m5 + logf(s5);
        int n = n0 + ty + i * 32;
        if (n < N) {
#pragma unroll
            for (int m = 0; m < 5; ++m) out[(size_t)n * H + jb + m] = lg[i][m] - lse;
        }
    }
}

// ================= launcher =================
extern "C" void kernel_launch(void* const* d_in, const int* in_sizes, int n_in,
                              void* d_out, int out_size, void* d_ws, size_t ws_size,
                              hipStream_t stream) {
    const float* x   = (const float*)d_in[0];
    const int* edges = (const int*)d_in[1];
    const float* W1a = (const float*)d_in[2];
    const float* b1a = (const float*)d_in[3];
    const float* W1b = (const float*)d_in[4];
    const float* b1b = (const float*)d_in[5];
    const float* W2a = (const float*)d_in[6];
    const float* b2a = (const float*)d_in[7];
    const float* W2b = (const float*)d_in[8];
    const float* b2b = (const float*)d_in[9];

    const int N = NNODES;
    const int E = in_sizes[1] / 2;
    const int* srcp = edges;
    const int* dstp = edges + E;

    auto au = [](size_t v) { return (v + 255) & ~(size_t)255; };
    char* p = (char*)d_ws;
    int* deg     = (int*)p; p += au((size_t)N * 4);
    int* offs    = (int*)p; p += au((size_t)(N + 1) * 4);
    int* cursor  = (int*)p; p += au((size_t)N * 4);
    int* lexcl   = (int*)p; p += au((size_t)N * 4);
    int* blksums = (int*)p; p += au((size_t)64 * 4);
    int* csr     = (int*)p; p += au((size_t)E * 4);
    float* bufA  = (float*)p; p += au((size_t)N * INC * 4);   // agg1 out (N x 100)
    float* bufB  = (float*)p; p += au((size_t)N * HIDC * 4);  // X1 / agg2 out
    float* bufC  = (float*)p; p += au((size_t)N * HIDC * 4);  // H1

    const int nb = (N + 1023) / 1024;  // 49

    // ---- CSR build
    hipMemsetAsync(deg, 0, (size_t)N * sizeof(int), stream);
    count_kernel<<<(E + 255) / 256, 256, 0, stream>>>(dstp, deg, E);
    scan_pass1<<<nb, 256, 0, stream>>>(deg, lexcl, blksums, N);
    scan_pass2<<<1, 64, 0, stream>>>(blksums, nb, offs + N);
    scan_pass3<<<(N + 255) / 256, 256, 0, stream>>>(lexcl, blksums, offs, cursor, N);
    scatter_kernel<<<(E + 255) / 256, 256, 0, stream>>>(srcp, dstp, cursor, csr, E);

    // ---- layer 1
    agg_v2<25><<<(N + 7) / 8, 256, 0, stream>>>((const float4*)x, offs, csr,
                                                (float4*)bufA, N);
    gemm128_v2<100, 25, true><<<(N + 63) / 64, 256, 0, stream>>>(bufA, W1a, b1a, bufB, N);
    gemm128_v2<128, 32, true><<<(N + 63) / 64, 256, 0, stream>>>(bufB, W1b, b1b, bufC, N);

    // ---- layer 2
    agg_v2<32><<<(N + 7) / 8, 256, 0, stream>>>((const float4*)bufC, offs, csr,
                                                (float4*)bufB, N);
    mlp2_fused<<<(N + 63) / 64, 256, 0, stream>>>(bufB, W2a, b2a, W2b, b2b,
                                                  (float*)d_out, N);
}

// Round 3
// 313.880 us; speedup vs baseline: 1.8023x; 1.0697x over previous
//
#include <hip/hip_runtime.h>

// ---------------- problem constants ----------------
#define NNODES 50000
#define INC 100
#define HIDC 128
#define OUTC 40

// ================= CSR build =================
__global__ __launch_bounds__(256) void count_kernel(const int* __restrict__ dst,
                                                    int* __restrict__ deg, int E) {
    int e = blockIdx.x * 256 + threadIdx.x;
    if (e < E) atomicAdd(&deg[dst[e]], 1);
}

__global__ __launch_bounds__(256) void scan_pass1(const int* __restrict__ deg,
                                                  int* __restrict__ lexcl,
                                                  int* __restrict__ blk_sums, int n) {
    __shared__ int wsum[4];
    int base = blockIdx.x * 1024;
    int t = threadIdx.x;
    int i0 = base + t * 4;
    int a = (i0 + 0 < n) ? deg[i0 + 0] : 0;
    int b = (i0 + 1 < n) ? deg[i0 + 1] : 0;
    int c = (i0 + 2 < n) ? deg[i0 + 2] : 0;
    int d = (i0 + 3 < n) ? deg[i0 + 3] : 0;
    int s4 = a + b + c + d;
    int lane = t & 63, w = t >> 6;
    int incl = s4;
#pragma unroll
    for (int off = 1; off < 64; off <<= 1) {
        int u = __shfl_up(incl, off);
        if (lane >= off) incl += u;
    }
    if (lane == 63) wsum[w] = incl;
    __syncthreads();
    int wbase = 0;
#pragma unroll
    for (int j = 0; j < 4; ++j)
        if (j < w) wbase += wsum[j];
    int excl = wbase + incl - s4;
    if (i0 + 0 < n) lexcl[i0 + 0] = excl;
    if (i0 + 1 < n) lexcl[i0 + 1] = excl + a;
    if (i0 + 2 < n) lexcl[i0 + 2] = excl + a + b;
    if (i0 + 3 < n) lexcl[i0 + 3] = excl + a + b + c;
    if (t == 255) blk_sums[blockIdx.x] = wbase + incl;
}

__global__ __launch_bounds__(64) void scan_pass2(int* __restrict__ blk_sums, int nb,
                                                 int* __restrict__ offs_end) {
    int lane = threadIdx.x;
    int v = (lane < nb) ? blk_sums[lane] : 0;
    int incl = v;
#pragma unroll
    for (int off = 1; off < 64; off <<= 1) {
        int u = __shfl_up(incl, off);
        if (lane >= off) incl += u;
    }
    if (lane < nb) blk_sums[lane] = incl - v;
    if (lane == 63) offs_end[0] = incl;
}

__global__ __launch_bounds__(256) void scan_pass3(const int* __restrict__ lexcl,
                                                  const int* __restrict__ blk_sums,
                                                  int* __restrict__ offs,
                                                  int* __restrict__ cursor, int n) {
    int i = blockIdx.x * 256 + threadIdx.x;
    if (i < n) {
        int v = lexcl[i] + blk_sums[i >> 10];
        offs[i] = v;
        cursor[i] = v;
    }
}

__global__ __launch_bounds__(256) void scatter_kernel(const int* __restrict__ src,
                                                      const int* __restrict__ dst,
                                                      int* __restrict__ cursor,
                                                      int* __restrict__ csr_src, int E) {
    int e = blockIdx.x * 256 + threadIdx.x;
    if (e < E) {
        int pos = atomicAdd(&cursor[dst[e]], 1);
        csr_src[pos] = src[e];
    }
}

// ================= GIN aggregation, 4-way unrolled (float4, 32 lanes/node) =================
template <int C4>
__global__ __launch_bounds__(256) void agg_wide(const float4* __restrict__ feat,
                                                const int* __restrict__ offs,
                                                const int* __restrict__ csr,
                                                float4* __restrict__ out, int N) {
    int node = blockIdx.x * 8 + (threadIdx.x >> 5);
    int l = threadIdx.x & 31;
    if (node >= N || l >= C4) return;
    int s = offs[node], e = offs[node + 1];
    float4 acc = feat[(size_t)node * C4 + l];
    int i = s;
    for (; i + 4 <= e; i += 4) {
        int n0 = csr[i], n1 = csr[i + 1], n2 = csr[i + 2], n3 = csr[i + 3];
        float4 v0 = feat[(size_t)n0 * C4 + l];
        float4 v1 = feat[(size_t)n1 * C4 + l];
        float4 v2 = feat[(size_t)n2 * C4 + l];
        float4 v3 = feat[(size_t)n3 * C4 + l];
        acc.x += v0.x + v1.x + v2.x + v3.x;
        acc.y += v0.y + v1.y + v2.y + v3.y;
        acc.z += v0.z + v1.z + v2.z + v3.z;
        acc.w += v0.w + v1.w + v2.w + v3.w;
    }
    for (; i < e; ++i) {
        int sn = csr[i];
        float4 v = feat[(size_t)sn * C4 + l];
        acc.x += v.x; acc.y += v.y; acc.z += v.z; acc.w += v.w;
    }
    out[(size_t)node * C4 + l] = acc;
}

// ================= 40-dim aggregation: 10 float4-lanes/node, 6 nodes/wave =================
__global__ __launch_bounds__(256) void agg40(const float4* __restrict__ T,
                                             const int* __restrict__ offs,
                                             const int* __restrict__ csr,
                                             float4* __restrict__ U, int N) {
    int wave = threadIdx.x >> 6;
    int lane = threadIdx.x & 63;
    int g = lane / 10;
    int sub = lane - g * 10;
    int node = blockIdx.x * 24 + wave * 6 + g;
    if (g >= 6 || node >= N) return;
    int s = offs[node], e = offs[node + 1];
    float4 acc = T[(size_t)node * 10 + sub];
    int i = s;
    for (; i + 4 <= e; i += 4) {
        int n0 = csr[i], n1 = csr[i + 1], n2 = csr[i + 2], n3 = csr[i + 3];
        float4 v0 = T[(size_t)n0 * 10 + sub];
        float4 v1 = T[(size_t)n1 * 10 + sub];
        float4 v2 = T[(size_t)n2 * 10 + sub];
        float4 v3 = T[(size_t)n3 * 10 + sub];
        acc.x += v0.x + v1.x + v2.x + v3.x;
        acc.y += v0.y + v1.y + v2.y + v3.y;
        acc.z += v0.z + v1.z + v2.z + v3.z;
        acc.w += v0.w + v1.w + v2.w + v3.w;
    }
    for (; i < e; ++i) {
        int sn = csr[i];
        float4 v = T[(size_t)sn * 10 + sub];
        acc.x += v.x; acc.y += v.y; acc.z += v.z; acc.w += v.w;
    }
    U[(size_t)node * 10 + sub] = acc;
}

// ================= register-tiled GEMM: out[N,128] = act(A[N,K] @ W[K,128] + b) =================
template <int K, int KC, bool RELU>
__global__ __launch_bounds__(256) void gemm128_v2(const float* __restrict__ A,
                                                  const float* __restrict__ W,
                                                  const float* __restrict__ bias,
                                                  float* __restrict__ out, int N) {
    constexpr int J = 128;
    constexpr int BM = 64;
    constexpr int LDA = K + 4;
    __shared__ float As[BM * LDA];
    __shared__ float Wc[KC * J];

    const int tid = threadIdx.x;
    const int n0 = blockIdx.x * BM;

    constexpr int K4 = K / 4;
    for (int idx = tid; idx < BM * K4; idx += 256) {
        int r = idx / K4, c4 = idx - r * K4;
        int n = n0 + r;
        float4 v = make_float4(0.f, 0.f, 0.f, 0.f);
        if (n < N) v = reinterpret_cast<const float4*>(A + (size_t)n * K)[c4];
        *reinterpret_cast<float4*>(&As[r * LDA + c4 * 4]) = v;
    }

    const int tx = tid & 15;
    const int ty = tid >> 4;
    const int jb = tx * 8;
    const int r0 = (ty + 0) * LDA;
    const int r1 = (ty + 16) * LDA;
    const int r2 = (ty + 32) * LDA;
    const int r3 = (ty + 48) * LDA;

    float acc[4][8];
    {
        float4 b0 = *reinterpret_cast<const float4*>(&bias[jb]);
        float4 b1 = *reinterpret_cast<const float4*>(&bias[jb + 4]);
        float bb[8] = {b0.x, b0.y, b0.z, b0.w, b1.x, b1.y, b1.z, b1.w};
#pragma unroll
        for (int i = 0; i < 4; ++i)
#pragma unroll
            for (int m = 0; m < 8; ++m) acc[i][m] = bb[m];
    }

    for (int kb = 0; kb < K; kb += KC) {
        __syncthreads();
        for (int idx = tid; idx < KC * (J / 4); idx += 256) {
            int r = idx >> 5, c4 = idx & 31;
            *reinterpret_cast<float4*>(&Wc[r * J + c4 * 4]) =
                *reinterpret_cast<const float4*>(&W[(size_t)(kb + r) * J + c4 * 4]);
        }
        __syncthreads();
#pragma unroll
        for (int k = 0; k < KC; ++k) {
            float a[4];
            a[0] = As[r0 + kb + k];
            a[1] = As[r1 + kb + k];
            a[2] = As[r2 + kb + k];
            a[3] = As[r3 + kb + k];
            float4 w0 = *reinterpret_cast<const float4*>(&Wc[k * J + jb]);
            float4 w1 = *reinterpret_cast<const float4*>(&Wc[k * J + jb + 4]);
            float w[8] = {w0.x, w0.y, w0.z, w0.w, w1.x, w1.y, w1.z, w1.w};
#pragma unroll
            for (int i = 0; i < 4; ++i)
#pragma unroll
                for (int m = 0; m < 8; ++m) acc[i][m] = fmaf(a[i], w[m], acc[i][m]);
        }
    }

    const int rows[4] = {ty, ty + 16, ty + 32, ty + 48};
#pragma unroll
    for (int i = 0; i < 4; ++i) {
        int n = n0 + rows[i];
        if (n < N) {
            float o[8];
#pragma unroll
            for (int m = 0; m < 8; ++m) o[m] = RELU ? fmaxf(acc[i][m], 0.f) : acc[i][m];
            *reinterpret_cast<float4*>(&out[(size_t)n * J + jb]) =
                make_float4(o[0], o[1], o[2], o[3]);
            *reinterpret_cast<float4*>(&out[(size_t)n * J + jb + 4]) =
                make_float4(o[4], o[5], o[6], o[7]);
        }
    }
}

// ================= T2 = H1[N,128] @ W2a[128,40]  (no bias, no relu) =================
__global__ __launch_bounds__(256) void gemm_t2(const float* __restrict__ A,
                                               const float* __restrict__ W,
                                               float* __restrict__ T, int N) {
    constexpr int K = 128, H = 40, BM = 64;
    constexpr int LDA = K + 4;   // 132
    constexpr int LDW = 44;
    __shared__ float As[BM * LDA];
    __shared__ float Ws[K * LDW];

    const int tid = threadIdx.x;
    const int n0 = blockIdx.x * BM;

    for (int idx = tid; idx < BM * (K / 4); idx += 256) {
        int r = idx >> 5, c4 = idx & 31;
        int n = n0 + r;
        float4 v = make_float4(0.f, 0.f, 0.f, 0.f);
        if (n < N) v = reinterpret_cast<const float4*>(A + (size_t)n * K)[c4];
        *reinterpret_cast<float4*>(&As[r * LDA + c4 * 4]) = v;
    }
    for (int idx = tid; idx < K * (H / 4); idx += 256) {
        int r = idx / 10, c4 = idx - r * 10;
        *reinterpret_cast<float4*>(&Ws[r * LDW + c4 * 4]) =
            *reinterpret_cast<const float4*>(&W[r * H + c4 * 4]);
    }
    __syncthreads();

    const int tx = tid & 7;
    const int ty = tid >> 3;  // 0..31
    const int jb = tx * 5;

    float acc[2][5] = {};
    const int r0 = ty * LDA, r1 = (ty + 32) * LDA;
#pragma unroll 8
    for (int k = 0; k < K; ++k) {
        float a0 = As[r0 + k];
        float a1 = As[r1 + k];
#pragma unroll
        for (int m = 0; m < 5; ++m) {
            float w = Ws[k * LDW + jb + m];
            acc[0][m] = fmaf(a0, w, acc[0][m]);
            acc[1][m] = fmaf(a1, w, acc[1][m]);
        }
    }
    int na = n0 + ty, nb2 = n0 + ty + 32;
    if (na < N) {
#pragma unroll
        for (int m = 0; m < 5; ++m) T[(size_t)na * H + jb + m] = acc[0][m];
    }
    if (nb2 < N) {
#pragma unroll
        for (int m = 0; m < 5; ++m) T[(size_t)nb2 * H + jb + m] = acc[1][m];
    }
}

// ================= epilogue: logits = relu(U + b2a) @ W2b + b2b ; out = log_softmax =================
// one wave per node, 4 nodes/block; t broadcast via __shfl
__global__ __launch_bounds__(256) void epi40(const float* __restrict__ U,
                                             const float* __restrict__ b2a,
                                             const float* __restrict__ W2b,
                                             const float* __restrict__ b2b,
                                             float* __restrict__ out, int N) {
    constexpr int H = 40, LDW = 44;
    __shared__ float Ws[H * LDW];
    __shared__ float ba[H], bb[H];
    for (int idx = threadIdx.x; idx < H * (H / 4); idx += 256) {
        int r = idx / 10, c4 = idx - r * 10;
        *reinterpret_cast<float4*>(&Ws[r * LDW + c4 * 4]) =
            *reinterpret_cast<const float4*>(&W2b[r * H + c4 * 4]);
    }
    if (threadIdx.x < H) {
        ba[threadIdx.x] = b2a[threadIdx.x];
        bb[threadIdx.x] = b2b[threadIdx.x];
    }
    __syncthreads();

    int wave = threadIdx.x >> 6;
    int lane = threadIdx.x & 63;
    int n = blockIdx.x * 4 + wave;
    if (n >= N) return;

    // lane j (j<40) holds t_j = relu(u_j + b2a_j)
    float t = 0.f;
    if (lane < H) t = fmaxf(U[(size_t)n * H + lane] + ba[lane], 0.f);

    float logit = -INFINITY;
    if (lane < H) {
        float a = bb[lane];
#pragma unroll 8
        for (int k = 0; k < H; ++k) {
            float tk = __shfl(t, k);
            a = fmaf(tk, Ws[k * LDW + lane], a);
        }
        logit = a;
    }
    float m = logit;
#pragma unroll
    for (int off = 32; off; off >>= 1) m = fmaxf(m, __shfl_xor(m, off));
    float ex = (lane < H) ? expf(logit - m) : 0.f;
    float s = ex;
#pragma unroll
    for (int off = 32; off; off >>= 1) s += __shfl_xor(s, off);
    if (lane < H) out[(size_t)n * H + lane] = logit - m - logf(s);
}

// ================= launcher =================
extern "C" void kernel_launch(void* const* d_in, const int* in_sizes, int n_in,
                              void* d_out, int out_size, void* d_ws, size_t ws_size,
                              hipStream_t stream) {
    const float* x   = (const float*)d_in[0];
    const int* edges = (const int*)d_in[1];
    const float* W1a = (const float*)d_in[2];
    const float* b1a = (const float*)d_in[3];
    const float* W1b = (const float*)d_in[4];
    const float* b1b = (const float*)d_in[5];
    const float* W2a = (const float*)d_in[6];
    const float* b2a = (const float*)d_in[7];
    const float* W2b = (const float*)d_in[8];
    const float* b2b = (const float*)d_in[9];

    const int N = NNODES;
    const int E = in_sizes[1] / 2;
    const int* srcp = edges;
    const int* dstp = edges + E;

    auto au = [](size_t v) { return (v + 255) & ~(size_t)255; };
    char* p = (char*)d_ws;
    int* deg     = (int*)p; p += au((size_t)N * 4);
    int* offs    = (int*)p; p += au((size_t)(N + 1) * 4);
    int* cursor  = (int*)p; p += au((size_t)N * 4);
    int* lexcl   = (int*)p; p += au((size_t)N * 4);
    int* blksums = (int*)p; p += au((size_t)64 * 4);
    int* csr     = (int*)p; p += au((size_t)E * 4);
    float* bufA  = (float*)p; p += au((size_t)N * INC * 4);   // agg1 out; later T2 + U (2 x N x 40)
    float* bufB  = (float*)p; p += au((size_t)N * HIDC * 4);  // X1
    float* bufC  = (float*)p; p += au((size_t)N * HIDC * 4);  // H1
    float* bufT  = bufA;                                      // N x 40 (T2) — bufA dead by then
    float* bufU  = bufA + (size_t)N * OUTC;                   // N x 40 (agg2 out)

    const int nb = (N + 1023) / 1024;  // 49

    // ---- CSR build
    hipMemsetAsync(deg, 0, (size_t)N * sizeof(int), stream);
    count_kernel<<<(E + 255) / 256, 256, 0, stream>>>(dstp, deg, E);
    scan_pass1<<<nb, 256, 0, stream>>>(deg, lexcl, blksums, N);
    scan_pass2<<<1, 64, 0, stream>>>(blksums, nb, offs + N);
    scan_pass3<<<(N + 255) / 256, 256, 0, stream>>>(lexcl, blksums, offs, cursor, N);
    scatter_kernel<<<(E + 255) / 256, 256, 0, stream>>>(srcp, dstp, cursor, csr, E);

    // ---- layer 1
    agg_wide<25><<<(N + 7) / 8, 256, 0, stream>>>((const float4*)x, offs, csr,
                                                  (float4*)bufA, N);
    gemm128_v2<100, 25, true><<<(N + 63) / 64, 256, 0, stream>>>(bufA, W1a, b1a, bufB, N);
    gemm128_v2<128, 32, true><<<(N + 63) / 64, 256, 0, stream>>>(bufB, W1b, b1b, bufC, N);

    // ---- layer 2 (reassociated: GEMM before aggregation, 40-dim gather)
    gemm_t2<<<(N + 63) / 64, 256, 0, stream>>>(bufC, W2a, bufT, N);
    agg40<<<(N + 23) / 24, 256, 0, stream>>>((const float4*)bufT, offs, csr,
                                             (float4*)bufU, N);
    epi40<<<(N + 3) / 4, 256, 0, stream>>>(bufU, b2a, W2b, b2b, (float*)d_out, N);
}

// Round 4
// 296.107 us; speedup vs baseline: 1.9104x; 1.0600x over previous
//
#include <hip/hip_runtime.h>

// ---------------- problem constants ----------------
#define NNODES 50000
#define INC 100
#define HIDC 128
#define OUTC 40
#define NBUCKET 8
#define BUCKET_SZ ((NNODES + NBUCKET - 1) / NBUCKET)   // 6250
#define SCHUNKS 256

// ================= CSR build =================
__global__ __launch_bounds__(256) void count_kernel(const int* __restrict__ dst,
                                                    int* __restrict__ deg, int E) {
    int e = blockIdx.x * 256 + threadIdx.x;
    if (e < E) atomicAdd(&deg[dst[e]], 1);
}

__global__ __launch_bounds__(256) void scan_pass1(const int* __restrict__ deg,
                                                  int* __restrict__ lexcl,
                                                  int* __restrict__ blk_sums, int n) {
    __shared__ int wsum[4];
    int base = blockIdx.x * 1024;
    int t = threadIdx.x;
    int i0 = base + t * 4;
    int a = (i0 + 0 < n) ? deg[i0 + 0] : 0;
    int b = (i0 + 1 < n) ? deg[i0 + 1] : 0;
    int c = (i0 + 2 < n) ? deg[i0 + 2] : 0;
    int d = (i0 + 3 < n) ? deg[i0 + 3] : 0;
    int s4 = a + b + c + d;
    int lane = t & 63, w = t >> 6;
    int incl = s4;
#pragma unroll
    for (int off = 1; off < 64; off <<= 1) {
        int u = __shfl_up(incl, off);
        if (lane >= off) incl += u;
    }
    if (lane == 63) wsum[w] = incl;
    __syncthreads();
    int wbase = 0;
#pragma unroll
    for (int j = 0; j < 4; ++j)
        if (j < w) wbase += wsum[j];
    int excl = wbase + incl - s4;
    if (i0 + 0 < n) lexcl[i0 + 0] = excl;
    if (i0 + 1 < n) lexcl[i0 + 1] = excl + a;
    if (i0 + 2 < n) lexcl[i0 + 2] = excl + a + b;
    if (i0 + 3 < n) lexcl[i0 + 3] = excl + a + b + c;
    if (t == 255) blk_sums[blockIdx.x] = wbase + incl;
}

__global__ __launch_bounds__(64) void scan_pass2(int* __restrict__ blk_sums, int nb,
                                                 int* __restrict__ offs_end) {
    int lane = threadIdx.x;
    int v = (lane < nb) ? blk_sums[lane] : 0;
    int incl = v;
#pragma unroll
    for (int off = 1; off < 64; off <<= 1) {
        int u = __shfl_up(incl, off);
        if (lane >= off) incl += u;
    }
    if (lane < nb) blk_sums[lane] = incl - v;
    if (lane == 63) offs_end[0] = incl;
}

__global__ __launch_bounds__(256) void scan_pass3(const int* __restrict__ lexcl,
                                                  const int* __restrict__ blk_sums,
                                                  int* __restrict__ offs,
                                                  int* __restrict__ cursor, int n) {
    int i = blockIdx.x * 256 + threadIdx.x;
    if (i < n) {
        int v = lexcl[i] + blk_sums[i >> 10];
        offs[i] = v;
        cursor[i] = v;
    }
}

// XCD-affine bucketed scatter: bucket b handled only by blocks with blockIdx%8==b
// (round-robin block->XCD) so each csr region is written from a single XCD's L2.
__global__ __launch_bounds__(256) void scatter_bucket(const int* __restrict__ src,
                                                      const int* __restrict__ dst,
                                                      int* __restrict__ cursor,
                                                      int* __restrict__ csr, int E) {
    int bucket = blockIdx.x & (NBUCKET - 1);
    int chunk = blockIdx.x >> 3;
    int lo = (int)((long long)E * chunk / SCHUNKS);
    int hi = (int)((long long)E * (chunk + 1) / SCHUNKS);
    int blo = bucket * BUCKET_SZ;
    int bhi = blo + BUCKET_SZ;
    for (int e = lo + (int)threadIdx.x; e < hi; e += 256) {
        int d = dst[e];
        if (d >= blo && d < bhi) {
            int pos = atomicAdd(&cursor[d], 1);
            csr[pos] = src[e];
        }
    }
}

// ================= GIN aggregation, 8-way unrolled (float4, 32 lanes/node) =================
template <int C4>
__global__ __launch_bounds__(256) void agg_wide(const float4* __restrict__ feat,
                                                const int* __restrict__ offs,
                                                const int* __restrict__ csr,
                                                float4* __restrict__ out, int N) {
    int node = blockIdx.x * 8 + (threadIdx.x >> 5);
    int l = threadIdx.x & 31;
    if (node >= N || l >= C4) return;
    int s = offs[node], e = offs[node + 1];
    float4 acc = feat[(size_t)node * C4 + l];
    int i = s;
    for (; i + 8 <= e; i += 8) {
        int n0 = csr[i], n1 = csr[i + 1], n2 = csr[i + 2], n3 = csr[i + 3];
        int n4 = csr[i + 4], n5 = csr[i + 5], n6 = csr[i + 6], n7 = csr[i + 7];
        float4 v0 = feat[(size_t)n0 * C4 + l];
        float4 v1 = feat[(size_t)n1 * C4 + l];
        float4 v2 = feat[(size_t)n2 * C4 + l];
        float4 v3 = feat[(size_t)n3 * C4 + l];
        float4 v4 = feat[(size_t)n4 * C4 + l];
        float4 v5 = feat[(size_t)n5 * C4 + l];
        float4 v6 = feat[(size_t)n6 * C4 + l];
        float4 v7 = feat[(size_t)n7 * C4 + l];
        acc.x += ((v0.x + v1.x) + (v2.x + v3.x)) + ((v4.x + v5.x) + (v6.x + v7.x));
        acc.y += ((v0.y + v1.y) + (v2.y + v3.y)) + ((v4.y + v5.y) + (v6.y + v7.y));
        acc.z += ((v0.z + v1.z) + (v2.z + v3.z)) + ((v4.z + v5.z) + (v6.z + v7.z));
        acc.w += ((v0.w + v1.w) + (v2.w + v3.w)) + ((v4.w + v5.w) + (v6.w + v7.w));
    }
    for (; i + 4 <= e; i += 4) {
        int n0 = csr[i], n1 = csr[i + 1], n2 = csr[i + 2], n3 = csr[i + 3];
        float4 v0 = feat[(size_t)n0 * C4 + l];
        float4 v1 = feat[(size_t)n1 * C4 + l];
        float4 v2 = feat[(size_t)n2 * C4 + l];
        float4 v3 = feat[(size_t)n3 * C4 + l];
        acc.x += (v0.x + v1.x) + (v2.x + v3.x);
        acc.y += (v0.y + v1.y) + (v2.y + v3.y);
        acc.z += (v0.z + v1.z) + (v2.z + v3.z);
        acc.w += (v0.w + v1.w) + (v2.w + v3.w);
    }
    for (; i < e; ++i) {
        int sn = csr[i];
        float4 v = feat[(size_t)sn * C4 + l];
        acc.x += v.x; acc.y += v.y; acc.z += v.z; acc.w += v.w;
    }
    out[(size_t)node * C4 + l] = acc;
}

// ================= 40-dim aggregation: 10 float4-lanes/node, 6 nodes/wave, 8-way =================
__global__ __launch_bounds__(256) void agg40(const float4* __restrict__ T,
                                             const int* __restrict__ offs,
                                             const int* __restrict__ csr,
                                             float4* __restrict__ U, int N) {
    int wave = threadIdx.x >> 6;
    int lane = threadIdx.x & 63;
    int g = lane / 10;
    int sub = lane - g * 10;
    int node = blockIdx.x * 24 + wave * 6 + g;
    if (g >= 6 || node >= N) return;
    int s = offs[node], e = offs[node + 1];
    float4 acc = T[(size_t)node * 10 + sub];
    int i = s;
    for (; i + 8 <= e; i += 8) {
        int n0 = csr[i], n1 = csr[i + 1], n2 = csr[i + 2], n3 = csr[i + 3];
        int n4 = csr[i + 4], n5 = csr[i + 5], n6 = csr[i + 6], n7 = csr[i + 7];
        float4 v0 = T[(size_t)n0 * 10 + sub];
        float4 v1 = T[(size_t)n1 * 10 + sub];
        float4 v2 = T[(size_t)n2 * 10 + sub];
        float4 v3 = T[(size_t)n3 * 10 + sub];
        float4 v4 = T[(size_t)n4 * 10 + sub];
        float4 v5 = T[(size_t)n5 * 10 + sub];
        float4 v6 = T[(size_t)n6 * 10 + sub];
        float4 v7 = T[(size_t)n7 * 10 + sub];
        acc.x += ((v0.x + v1.x) + (v2.x + v3.x)) + ((v4.x + v5.x) + (v6.x + v7.x));
        acc.y += ((v0.y + v1.y) + (v2.y + v3.y)) + ((v4.y + v5.y) + (v6.y + v7.y));
        acc.z += ((v0.z + v1.z) + (v2.z + v3.z)) + ((v4.z + v5.z) + (v6.z + v7.z));
        acc.w += ((v0.w + v1.w) + (v2.w + v3.w)) + ((v4.w + v5.w) + (v6.w + v7.w));
    }
    for (; i + 4 <= e; i += 4) {
        int n0 = csr[i], n1 = csr[i + 1], n2 = csr[i + 2], n3 = csr[i + 3];
        float4 v0 = T[(size_t)n0 * 10 + sub];
        float4 v1 = T[(size_t)n1 * 10 + sub];
        float4 v2 = T[(size_t)n2 * 10 + sub];
        float4 v3 = T[(size_t)n3 * 10 + sub];
        acc.x += (v0.x + v1.x) + (v2.x + v3.x);
        acc.y += (v0.y + v1.y) + (v2.y + v3.y);
        acc.z += (v0.z + v1.z) + (v2.z + v3.z);
        acc.w += (v0.w + v1.w) + (v2.w + v3.w);
    }
    for (; i < e; ++i) {
        int sn = csr[i];
        float4 v = T[(size_t)sn * 10 + sub];
        acc.x += v.x; acc.y += v.y; acc.z += v.z; acc.w += v.w;
    }
    U[(size_t)node * 10 + sub] = acc;
}

// ================= register-tiled GEMM: out[N,128] = act(A[N,K] @ W[K,128] + b) =================
template <int K, int KC, bool RELU>
__global__ __launch_bounds__(256) void gemm128_v2(const float* __restrict__ A,
                                                  const float* __restrict__ W,
                                                  const float* __restrict__ bias,
                                                  float* __restrict__ out, int N) {
    constexpr int J = 128;
    constexpr int BM = 64;
    constexpr int LDA = K + 4;
    __shared__ float As[BM * LDA];
    __shared__ float Wc[KC * J];

    const int tid = threadIdx.x;
    const int n0 = blockIdx.x * BM;

    constexpr int K4 = K / 4;
    for (int idx = tid; idx < BM * K4; idx += 256) {
        int r = idx / K4, c4 = idx - r * K4;
        int n = n0 + r;
        float4 v = make_float4(0.f, 0.f, 0.f, 0.f);
        if (n < N) v = reinterpret_cast<const float4*>(A + (size_t)n * K)[c4];
        *reinterpret_cast<float4*>(&As[r * LDA + c4 * 4]) = v;
    }

    const int tx = tid & 15;
    const int ty = tid >> 4;
    const int jb = tx * 8;
    const int r0 = (ty + 0) * LDA;
    const int r1 = (ty + 16) * LDA;
    const int r2 = (ty + 32) * LDA;
    const int r3 = (ty + 48) * LDA;

    float acc[4][8];
    {
        float4 b0 = *reinterpret_cast<const float4*>(&bias[jb]);
        float4 b1 = *reinterpret_cast<const float4*>(&bias[jb + 4]);
        float bb[8] = {b0.x, b0.y, b0.z, b0.w, b1.x, b1.y, b1.z, b1.w};
#pragma unroll
        for (int i = 0; i < 4; ++i)
#pragma unroll
            for (int m = 0; m < 8; ++m) acc[i][m] = bb[m];
    }

    for (int kb = 0; kb < K; kb += KC) {
        __syncthreads();
        for (int idx = tid; idx < KC * (J / 4); idx += 256) {
            int r = idx >> 5, c4 = idx & 31;
            *reinterpret_cast<float4*>(&Wc[r * J + c4 * 4]) =
                *reinterpret_cast<const float4*>(&W[(size_t)(kb + r) * J + c4 * 4]);
        }
        __syncthreads();
#pragma unroll
        for (int k = 0; k < KC; ++k) {
            float a[4];
            a[0] = As[r0 + kb + k];
            a[1] = As[r1 + kb + k];
            a[2] = As[r2 + kb + k];
            a[3] = As[r3 + kb + k];
            float4 w0 = *reinterpret_cast<const float4*>(&Wc[k * J + jb]);
            float4 w1 = *reinterpret_cast<const float4*>(&Wc[k * J + jb + 4]);
            float w[8] = {w0.x, w0.y, w0.z, w0.w, w1.x, w1.y, w1.z, w1.w};
#pragma unroll
            for (int i = 0; i < 4; ++i)
#pragma unroll
                for (int m = 0; m < 8; ++m) acc[i][m] = fmaf(a[i], w[m], acc[i][m]);
        }
    }

    const int rows[4] = {ty, ty + 16, ty + 32, ty + 48};
#pragma unroll
    for (int i = 0; i < 4; ++i) {
        int n = n0 + rows[i];
        if (n < N) {
            float o[8];
#pragma unroll
            for (int m = 0; m < 8; ++m) o[m] = RELU ? fmaxf(acc[i][m], 0.f) : acc[i][m];
            *reinterpret_cast<float4*>(&out[(size_t)n * J + jb]) =
                make_float4(o[0], o[1], o[2], o[3]);
            *reinterpret_cast<float4*>(&out[(size_t)n * J + jb + 4]) =
                make_float4(o[4], o[5], o[6], o[7]);
        }
    }
}

// ================= T2 = H1[N,128] @ W2a[128,40]  (no bias, no relu) =================
__global__ __launch_bounds__(256) void gemm_t2(const float* __restrict__ A,
                                               const float* __restrict__ W,
                                               float* __restrict__ T, int N) {
    constexpr int K = 128, H = 40, BM = 64;
    constexpr int LDA = K + 4;   // 132
    constexpr int LDW = 44;
    __shared__ float As[BM * LDA];
    __shared__ float Ws[K * LDW];

    const int tid = threadIdx.x;
    const int n0 = blockIdx.x * BM;

    for (int idx = tid; idx < BM * (K / 4); idx += 256) {
        int r = idx >> 5, c4 = idx & 31;
        int n = n0 + r;
        float4 v = make_float4(0.f, 0.f, 0.f, 0.f);
        if (n < N) v = reinterpret_cast<const float4*>(A + (size_t)n * K)[c4];
        *reinterpret_cast<float4*>(&As[r * LDA + c4 * 4]) = v;
    }
    for (int idx = tid; idx < K * (H / 4); idx += 256) {
        int r = idx / 10, c4 = idx - r * 10;
        *reinterpret_cast<float4*>(&Ws[r * LDW + c4 * 4]) =
            *reinterpret_cast<const float4*>(&W[r * H + c4 * 4]);
    }
    __syncthreads();

    const int tx = tid & 7;
    const int ty = tid >> 3;  // 0..31
    const int jb = tx * 5;

    float acc[2][5] = {};
    const int r0 = ty * LDA, r1 = (ty + 32) * LDA;
#pragma unroll 8
    for (int k = 0; k < K; ++k) {
        float a0 = As[r0 + k];
        float a1 = As[r1 + k];
#pragma unroll
        for (int m = 0; m < 5; ++m) {
            float w = Ws[k * LDW + jb + m];
            acc[0][m] = fmaf(a0, w, acc[0][m]);
            acc[1][m] = fmaf(a1, w, acc[1][m]);
        }
    }
    int na = n0 + ty, nb2 = n0 + ty + 32;
    if (na < N) {
#pragma unroll
        for (int m = 0; m < 5; ++m) T[(size_t)na * H + jb + m] = acc[0][m];
    }
    if (nb2 < N) {
#pragma unroll
        for (int m = 0; m < 5; ++m) T[(size_t)nb2 * H + jb + m] = acc[1][m];
    }
}

// ================= epilogue: logits = relu(U + b2a) @ W2b + b2b ; out = log_softmax =================
__global__ __launch_bounds__(256) void epi40(const float* __restrict__ U,
                                             const float* __restrict__ b2a,
                                             const float* __restrict__ W2b,
                                             const float* __restrict__ b2b,
                                             float* __restrict__ out, int N) {
    constexpr int H = 40, LDW = 44;
    __shared__ float Ws[H * LDW];
    __shared__ float ba[H], bb[H];
    for (int idx = threadIdx.x; idx < H * (H / 4); idx += 256) {
        int r = idx / 10, c4 = idx - r * 10;
        *reinterpret_cast<float4*>(&Ws[r * LDW + c4 * 4]) =
            *reinterpret_cast<const float4*>(&W2b[r * H + c4 * 4]);
    }
    if (threadIdx.x < H) {
        ba[threadIdx.x] = b2a[threadIdx.x];
        bb[threadIdx.x] = b2b[threadIdx.x];
    }
    __syncthreads();

    int wave = threadIdx.x >> 6;
    int lane = threadIdx.x & 63;
    int n = blockIdx.x * 4 + wave;
    if (n >= N) return;

    float t = 0.f;
    if (lane < H) t = fmaxf(U[(size_t)n * H + lane] + ba[lane], 0.f);

    float logit = -INFINITY;
    if (lane < H) {
        float a = bb[lane];
#pragma unroll 8
        for (int k = 0; k < H; ++k) {
            float tk = __shfl(t, k);
            a = fmaf(tk, Ws[k * LDW + lane], a);
        }
        logit = a;
    }
    float m = logit;
#pragma unroll
    for (int off = 32; off; off >>= 1) m = fmaxf(m, __shfl_xor(m, off));
    float ex = (lane < H) ? expf(logit - m) : 0.f;
    float s = ex;
#pragma unroll
    for (int off = 32; off; off >>= 1) s += __shfl_xor(s, off);
    if (lane < H) out[(size_t)n * H + lane] = logit - m - logf(s);
}

// ================= launcher =================
extern "C" void kernel_launch(void* const* d_in, const int* in_sizes, int n_in,
                              void* d_out, int out_size, void* d_ws, size_t ws_size,
                              hipStream_t stream) {
    const float* x   = (const float*)d_in[0];
    const int* edges = (const int*)d_in[1];
    const float* W1a = (const float*)d_in[2];
    const float* b1a = (const float*)d_in[3];
    const float* W1b = (const float*)d_in[4];
    const float* b1b = (const float*)d_in[5];
    const float* W2a = (const float*)d_in[6];
    const float* b2a = (const float*)d_in[7];
    const float* W2b = (const float*)d_in[8];
    const float* b2b = (const float*)d_in[9];

    const int N = NNODES;
    const int E = in_sizes[1] / 2;
    const int* srcp = edges;
    const int* dstp = edges + E;

    auto au = [](size_t v) { return (v + 255) & ~(size_t)255; };
    char* p = (char*)d_ws;
    int* deg     = (int*)p; p += au((size_t)N * 4);
    int* offs    = (int*)p; p += au((size_t)(N + 1) * 4);
    int* cursor  = (int*)p; p += au((size_t)N * 4);
    int* lexcl   = (int*)p; p += au((size_t)N * 4);
    int* blksums = (int*)p; p += au((size_t)64 * 4);
    int* csr     = (int*)p; p += au((size_t)E * 4);
    float* bufA  = (float*)p; p += au((size_t)N * INC * 4);   // agg1 out; later T2 + U
    float* bufB  = (float*)p; p += au((size_t)N * HIDC * 4);  // X1
    float* bufC  = (float*)p; p += au((size_t)N * HIDC * 4);  // H1
    float* bufT  = bufA;                                      // N x 40 (T2)
    float* bufU  = bufA + (size_t)N * OUTC;                   // N x 40 (agg2 out)

    const int nb = (N + 1023) / 1024;  // 49

    // ---- CSR build
    hipMemsetAsync(deg, 0, (size_t)N * sizeof(int), stream);
    count_kernel<<<(E + 255) / 256, 256, 0, stream>>>(dstp, deg, E);
    scan_pass1<<<nb, 256, 0, stream>>>(deg, lexcl, blksums, N);
    scan_pass2<<<1, 64, 0, stream>>>(blksums, nb, offs + N);
    scan_pass3<<<(N + 255) / 256, 256, 0, stream>>>(lexcl, blksums, offs, cursor, N);
    scatter_bucket<<<NBUCKET * SCHUNKS, 256, 0, stream>>>(srcp, dstp, cursor, csr, E);

    // ---- layer 1
    agg_wide<25><<<(N + 7) / 8, 256, 0, stream>>>((const float4*)x, offs, csr,
                                                  (float4*)bufA, N);
    gemm128_v2<100, 25, true><<<(N + 63) / 64, 256, 0, stream>>>(bufA, W1a, b1a, bufB, N);
    gemm128_v2<128, 32, true><<<(N + 63) / 64, 256, 0, stream>>>(bufB, W1b, b1b, bufC, N);

    // ---- layer 2 (reassociated: GEMM before aggregation, 40-dim gather)
    gemm_t2<<<(N + 63) / 64, 256, 0, stream>>>(bufC, W2a, bufT, N);
    agg40<<<(N + 23) / 24, 256, 0, stream>>>((const float4*)bufT, offs, csr,
                                             (float4*)bufU, N);
    epi40<<<(N + 3) / 4, 256, 0, stream>>>(bufU, b2a, W2b, b2b, (float*)d_out, N);
}

// Round 5
// 274.260 us; speedup vs baseline: 2.0626x; 1.0797x over previous
//
#include <hip/hip_runtime.h>

// ---------------- problem constants ----------------
#define NNODES 50000
#define INC 100
#define HIDC 128
#define OUTC 40
#define NBUCKET 8
#define BUCKET_SZ ((NNODES + NBUCKET - 1) / NBUCKET)   // 6250
#define SCHUNKS 256

// bf16 helpers (RNE pack, shift unpack)
__device__ __forceinline__ unsigned short f2bf(float f) {
    unsigned int u = __float_as_uint(f);
    unsigned int r = (u + 0x7FFFu + ((u >> 16) & 1u)) >> 16;
    return (unsigned short)r;
}
__device__ __forceinline__ unsigned int pack2(float a, float b) {
    return (unsigned int)f2bf(a) | ((unsigned int)f2bf(b) << 16);
}
__device__ __forceinline__ float4 bf4(uint2 a) {
    return make_float4(__uint_as_float(a.x << 16), __uint_as_float(a.x & 0xFFFF0000u),
                       __uint_as_float(a.y << 16), __uint_as_float(a.y & 0xFFFF0000u));
}

// ================= x -> bf16 table =================
__global__ __launch_bounds__(256) void cast_x_bf16(const float2* __restrict__ x2,
                                                   unsigned int* __restrict__ xh, int n2) {
    int i = blockIdx.x * 256 + threadIdx.x;
    if (i < n2) {
        float2 v = x2[i];
        xh[i] = pack2(v.x, v.y);
    }
}

// ================= CSR build =================
__global__ __launch_bounds__(256) void count_kernel(const int* __restrict__ dst,
                                                    int* __restrict__ deg, int E) {
    int e = blockIdx.x * 256 + threadIdx.x;
    if (e < E) atomicAdd(&deg[dst[e]], 1);
}

__global__ __launch_bounds__(256) void scan_pass1(const int* __restrict__ deg,
                                                  int* __restrict__ lexcl,
                                                  int* __restrict__ blk_sums, int n) {
    __shared__ int wsum[4];
    int base = blockIdx.x * 1024;
    int t = threadIdx.x;
    int i0 = base + t * 4;
    int a = (i0 + 0 < n) ? deg[i0 + 0] : 0;
    int b = (i0 + 1 < n) ? deg[i0 + 1] : 0;
    int c = (i0 + 2 < n) ? deg[i0 + 2] : 0;
    int d = (i0 + 3 < n) ? deg[i0 + 3] : 0;
    int s4 = a + b + c + d;
    int lane = t & 63, w = t >> 6;
    int incl = s4;
#pragma unroll
    for (int off = 1; off < 64; off <<= 1) {
        int u = __shfl_up(incl, off);
        if (lane >= off) incl += u;
    }
    if (lane == 63) wsum[w] = incl;
    __syncthreads();
    int wbase = 0;
#pragma unroll
    for (int j = 0; j < 4; ++j)
        if (j < w) wbase += wsum[j];
    int excl = wbase + incl - s4;
    if (i0 + 0 < n) lexcl[i0 + 0] = excl;
    if (i0 + 1 < n) lexcl[i0 + 1] = excl + a;
    if (i0 + 2 < n) lexcl[i0 + 2] = excl + a + b;
    if (i0 + 3 < n) lexcl[i0 + 3] = excl + a + b + c;
    if (t == 255) blk_sums[blockIdx.x] = wbase + incl;
}

__global__ __launch_bounds__(64) void scan_pass2(int* __restrict__ blk_sums, int nb,
                                                 int* __restrict__ offs_end) {
    int lane = threadIdx.x;
    int v = (lane < nb) ? blk_sums[lane] : 0;
    int incl = v;
#pragma unroll
    for (int off = 1; off < 64; off <<= 1) {
        int u = __shfl_up(incl, off);
        if (lane >= off) incl += u;
    }
    if (lane < nb) blk_sums[lane] = incl - v;
    if (lane == 63) offs_end[0] = incl;
}

__global__ __launch_bounds__(256) void scan_pass3(const int* __restrict__ lexcl,
                                                  const int* __restrict__ blk_sums,
                                                  int* __restrict__ offs,
                                                  int* __restrict__ cursor, int n) {
    int i = blockIdx.x * 256 + threadIdx.x;
    if (i < n) {
        int v = lexcl[i] + blk_sums[i >> 10];
        offs[i] = v;
        cursor[i] = v;
    }
}

// XCD-affine bucketed scatter (blockIdx%8 -> XCD -> csr region)
__global__ __launch_bounds__(256) void scatter_bucket(const int* __restrict__ src,
                                                      const int* __restrict__ dst,
                                                      int* __restrict__ cursor,
                                                      int* __restrict__ csr, int E) {
    int bucket = blockIdx.x & (NBUCKET - 1);
    int chunk = blockIdx.x >> 3;
    int lo = (int)((long long)E * chunk / SCHUNKS);
    int hi = (int)((long long)E * (chunk + 1) / SCHUNKS);
    int blo = bucket * BUCKET_SZ;
    int bhi = blo + BUCKET_SZ;
    for (int e = lo + (int)threadIdx.x; e < hi; e += 256) {
        int d = dst[e];
        if (d >= blo && d < bhi) {
            int pos = atomicAdd(&cursor[d], 1);
            csr[pos] = src[e];
        }
    }
}

// ================= layer-1 aggregation: bf16 neighbor gather, fp32 self + acc =================
// 32 lanes/node (25 active), 8 nodes/block. C=100: row = 25 uint2 (bf16) / 25 float4 (fp32).
__global__ __launch_bounds__(256) void agg_wide_bf(const float4* __restrict__ self,
                                                   const uint2* __restrict__ featbf,
                                                   const int* __restrict__ offs,
                                                   const int* __restrict__ csr,
                                                   float4* __restrict__ out, int N) {
    constexpr int C4 = 25;
    int node = blockIdx.x * 8 + (threadIdx.x >> 5);
    int l = threadIdx.x & 31;
    if (node >= N || l >= C4) return;
    int s = offs[node], e = offs[node + 1];
    float4 acc = self[(size_t)node * C4 + l];
    int i = s;
    for (; i + 8 <= e; i += 8) {
        int n0 = csr[i], n1 = csr[i + 1], n2 = csr[i + 2], n3 = csr[i + 3];
        int n4 = csr[i + 4], n5 = csr[i + 5], n6 = csr[i + 6], n7 = csr[i + 7];
        float4 v0 = bf4(featbf[(size_t)n0 * C4 + l]);
        float4 v1 = bf4(featbf[(size_t)n1 * C4 + l]);
        float4 v2 = bf4(featbf[(size_t)n2 * C4 + l]);
        float4 v3 = bf4(featbf[(size_t)n3 * C4 + l]);
        float4 v4 = bf4(featbf[(size_t)n4 * C4 + l]);
        float4 v5 = bf4(featbf[(size_t)n5 * C4 + l]);
        float4 v6 = bf4(featbf[(size_t)n6 * C4 + l]);
        float4 v7 = bf4(featbf[(size_t)n7 * C4 + l]);
        acc.x += ((v0.x + v1.x) + (v2.x + v3.x)) + ((v4.x + v5.x) + (v6.x + v7.x));
        acc.y += ((v0.y + v1.y) + (v2.y + v3.y)) + ((v4.y + v5.y) + (v6.y + v7.y));
        acc.z += ((v0.z + v1.z) + (v2.z + v3.z)) + ((v4.z + v5.z) + (v6.z + v7.z));
        acc.w += ((v0.w + v1.w) + (v2.w + v3.w)) + ((v4.w + v5.w) + (v6.w + v7.w));
    }
    for (; i + 4 <= e; i += 4) {
        int n0 = csr[i], n1 = csr[i + 1], n2 = csr[i + 2], n3 = csr[i + 3];
        float4 v0 = bf4(featbf[(size_t)n0 * C4 + l]);
        float4 v1 = bf4(featbf[(size_t)n1 * C4 + l]);
        float4 v2 = bf4(featbf[(size_t)n2 * C4 + l]);
        float4 v3 = bf4(featbf[(size_t)n3 * C4 + l]);
        acc.x += (v0.x + v1.x) + (v2.x + v3.x);
        acc.y += (v0.y + v1.y) + (v2.y + v3.y);
        acc.z += (v0.z + v1.z) + (v2.z + v3.z);
        acc.w += (v0.w + v1.w) + (v2.w + v3.w);
    }
    for (; i < e; ++i) {
        int sn = csr[i];
        float4 v = bf4(featbf[(size_t)sn * C4 + l]);
        acc.x += v.x; acc.y += v.y; acc.z += v.z; acc.w += v.w;
    }
    out[(size_t)node * C4 + l] = acc;
}

// ================= 40-dim aggregation: bf16 gather, fp32 self + acc =================
// 10 lanes/node, 6 nodes/wave. row = 10 uint2 (bf16) / 10 float4 (fp32).
__global__ __launch_bounds__(256) void agg40_bf(const float4* __restrict__ Tself,
                                                const uint2* __restrict__ Tbf,
                                                const int* __restrict__ offs,
                                                const int* __restrict__ csr,
                                                float4* __restrict__ U, int N) {
    int wave = threadIdx.x >> 6;
    int lane = threadIdx.x & 63;
    int g = lane / 10;
    int sub = lane - g * 10;
    int node = blockIdx.x * 24 + wave * 6 + g;
    if (g >= 6 || node >= N) return;
    int s = offs[node], e = offs[node + 1];
    float4 acc = Tself[(size_t)node * 10 + sub];
    int i = s;
    for (; i + 8 <= e; i += 8) {
        int n0 = csr[i], n1 = csr[i + 1], n2 = csr[i + 2], n3 = csr[i + 3];
        int n4 = csr[i + 4], n5 = csr[i + 5], n6 = csr[i + 6], n7 = csr[i + 7];
        float4 v0 = bf4(Tbf[(size_t)n0 * 10 + sub]);
        float4 v1 = bf4(Tbf[(size_t)n1 * 10 + sub]);
        float4 v2 = bf4(Tbf[(size_t)n2 * 10 + sub]);
        float4 v3 = bf4(Tbf[(size_t)n3 * 10 + sub]);
        float4 v4 = bf4(Tbf[(size_t)n4 * 10 + sub]);
        float4 v5 = bf4(Tbf[(size_t)n5 * 10 + sub]);
        float4 v6 = bf4(Tbf[(size_t)n6 * 10 + sub]);
        float4 v7 = bf4(Tbf[(size_t)n7 * 10 + sub]);
        acc.x += ((v0.x + v1.x) + (v2.x + v3.x)) + ((v4.x + v5.x) + (v6.x + v7.x));
        acc.y += ((v0.y + v1.y) + (v2.y + v3.y)) + ((v4.y + v5.y) + (v6.y + v7.y));
        acc.z += ((v0.z + v1.z) + (v2.z + v3.z)) + ((v4.z + v5.z) + (v6.z + v7.z));
        acc.w += ((v0.w + v1.w) + (v2.w + v3.w)) + ((v4.w + v5.w) + (v6.w + v7.w));
    }
    for (; i + 4 <= e; i += 4) {
        int n0 = csr[i], n1 = csr[i + 1], n2 = csr[i + 2], n3 = csr[i + 3];
        float4 v0 = bf4(Tbf[(size_t)n0 * 10 + sub]);
        float4 v1 = bf4(Tbf[(size_t)n1 * 10 + sub]);
        float4 v2 = bf4(Tbf[(size_t)n2 * 10 + sub]);
        float4 v3 = bf4(Tbf[(size_t)n3 * 10 + sub]);
        acc.x += (v0.x + v1.x) + (v2.x + v3.x);
        acc.y += (v0.y + v1.y) + (v2.y + v3.y);
        acc.z += (v0.z + v1.z) + (v2.z + v3.z);
        acc.w += (v0.w + v1.w) + (v2.w + v3.w);
    }
    for (; i < e; ++i) {
        int sn = csr[i];
        float4 v = bf4(Tbf[(size_t)sn * 10 + sub]);
        acc.x += v.x; acc.y += v.y; acc.z += v.z; acc.w += v.w;
    }
    U[(size_t)node * 10 + sub] = acc;
}

// ================= register-tiled GEMM: out[N,128] = act(A[N,K] @ W[K,128] + b) =================
template <int K, int KC, bool RELU>
__global__ __launch_bounds__(256) void gemm128_v2(const float* __restrict__ A,
                                                  const float* __restrict__ W,
                                                  const float* __restrict__ bias,
                                                  float* __restrict__ out, int N) {
    constexpr int J = 128;
    constexpr int BM = 64;
    constexpr int LDA = K + 4;
    __shared__ float As[BM * LDA];
    __shared__ float Wc[KC * J];

    const int tid = threadIdx.x;
    const int n0 = blockIdx.x * BM;

    constexpr int K4 = K / 4;
    for (int idx = tid; idx < BM * K4; idx += 256) {
        int r = idx / K4, c4 = idx - r * K4;
        int n = n0 + r;
        float4 v = make_float4(0.f, 0.f, 0.f, 0.f);
        if (n < N) v = reinterpret_cast<const float4*>(A + (size_t)n * K)[c4];
        *reinterpret_cast<float4*>(&As[r * LDA + c4 * 4]) = v;
    }

    const int tx = tid & 15;
    const int ty = tid >> 4;
    const int jb = tx * 8;
    const int r0 = (ty + 0) * LDA;
    const int r1 = (ty + 16) * LDA;
    const int r2 = (ty + 32) * LDA;
    const int r3 = (ty + 48) * LDA;

    float acc[4][8];
    {
        float4 b0 = *reinterpret_cast<const float4*>(&bias[jb]);
        float4 b1 = *reinterpret_cast<const float4*>(&bias[jb + 4]);
        float bb[8] = {b0.x, b0.y, b0.z, b0.w, b1.x, b1.y, b1.z, b1.w};
#pragma unroll
        for (int i = 0; i < 4; ++i)
#pragma unroll
            for (int m = 0; m < 8; ++m) acc[i][m] = bb[m];
    }

    for (int kb = 0; kb < K; kb += KC) {
        __syncthreads();
        for (int idx = tid; idx < KC * (J / 4); idx += 256) {
            int r = idx >> 5, c4 = idx & 31;
            *reinterpret_cast<float4*>(&Wc[r * J + c4 * 4]) =
                *reinterpret_cast<const float4*>(&W[(size_t)(kb + r) * J + c4 * 4]);
        }
        __syncthreads();
#pragma unroll
        for (int k = 0; k < KC; ++k) {
            float a[4];
            a[0] = As[r0 + kb + k];
            a[1] = As[r1 + kb + k];
            a[2] = As[r2 + kb + k];
            a[3] = As[r3 + kb + k];
            float4 w0 = *reinterpret_cast<const float4*>(&Wc[k * J + jb]);
            float4 w1 = *reinterpret_cast<const float4*>(&Wc[k * J + jb + 4]);
            float w[8] = {w0.x, w0.y, w0.z, w0.w, w1.x, w1.y, w1.z, w1.w};
#pragma unroll
            for (int i = 0; i < 4; ++i)
#pragma unroll
                for (int m = 0; m < 8; ++m) acc[i][m] = fmaf(a[i], w[m], acc[i][m]);
        }
    }

    const int rows[4] = {ty, ty + 16, ty + 32, ty + 48};
#pragma unroll
    for (int i = 0; i < 4; ++i) {
        int n = n0 + rows[i];
        if (n < N) {
            float o[8];
#pragma unroll
            for (int m = 0; m < 8; ++m) o[m] = RELU ? fmaxf(acc[i][m], 0.f) : acc[i][m];
            *reinterpret_cast<float4*>(&out[(size_t)n * J + jb]) =
                make_float4(o[0], o[1], o[2], o[3]);
            *reinterpret_cast<float4*>(&out[(size_t)n * J + jb + 4]) =
                make_float4(o[4], o[5], o[6], o[7]);
        }
    }
}

// ================= T2 = H1[N,128] @ W2a[128,40]  (fp32 + bf16 copies) =================
__global__ __launch_bounds__(256) void gemm_t2(const float* __restrict__ A,
                                               const float* __restrict__ W,
                                               float* __restrict__ T,
                                               unsigned short* __restrict__ Tb, int N) {
    constexpr int K = 128, H = 40, BM = 64;
    constexpr int LDA = K + 4;   // 132
    constexpr int LDW = 44;
    __shared__ float As[BM * LDA];
    __shared__ float Ws[K * LDW];

    const int tid = threadIdx.x;
    const int n0 = blockIdx.x * BM;

    for (int idx = tid; idx < BM * (K / 4); idx += 256) {
        int r = idx >> 5, c4 = idx & 31;
        int n = n0 + r;
        float4 v = make_float4(0.f, 0.f, 0.f, 0.f);
        if (n < N) v = reinterpret_cast<const float4*>(A + (size_t)n * K)[c4];
        *reinterpret_cast<float4*>(&As[r * LDA + c4 * 4]) = v;
    }
    for (int idx = tid; idx < K * (H / 4); idx += 256) {
        int r = idx / 10, c4 = idx - r * 10;
        *reinterpret_cast<float4*>(&Ws[r * LDW + c4 * 4]) =
            *reinterpret_cast<const float4*>(&W[r * H + c4 * 4]);
    }
    __syncthreads();

    const int tx = tid & 7;
    const int ty = tid >> 3;  // 0..31
    const int jb = tx * 5;

    float acc[2][5] = {};
    const int r0 = ty * LDA, r1 = (ty + 32) * LDA;
#pragma unroll 8
    for (int k = 0; k < K; ++k) {
        float a0 = As[r0 + k];
        float a1 = As[r1 + k];
#pragma unroll
        for (int m = 0; m < 5; ++m) {
            float w = Ws[k * LDW + jb + m];
            acc[0][m] = fmaf(a0, w, acc[0][m]);
            acc[1][m] = fmaf(a1, w, acc[1][m]);
        }
    }
    int na = n0 + ty, nb2 = n0 + ty + 32;
    if (na < N) {
#pragma unroll
        for (int m = 0; m < 5; ++m) {
            T[(size_t)na * H + jb + m] = acc[0][m];
            Tb[(size_t)na * H + jb + m] = f2bf(acc[0][m]);
        }
    }
    if (nb2 < N) {
#pragma unroll
        for (int m = 0; m < 5; ++m) {
            T[(size_t)nb2 * H + jb + m] = acc[1][m];
            Tb[(size_t)nb2 * H + jb + m] = f2bf(acc[1][m]);
        }
    }
}

// ================= epilogue: logits = relu(U + b2a) @ W2b + b2b ; out = log_softmax =================
__global__ __launch_bounds__(256) void epi40(const float* __restrict__ U,
                                             const float* __restrict__ b2a,
                                             const float* __restrict__ W2b,
                                             const float* __restrict__ b2b,
                                             float* __restrict__ out, int N) {
    constexpr int H = 40, LDW = 44;
    __shared__ float Ws[H * LDW];
    __shared__ float ba[H], bb[H];
    for (int idx = threadIdx.x; idx < H * (H / 4); idx += 256) {
        int r = idx / 10, c4 = idx - r * 10;
        *reinterpret_cast<float4*>(&Ws[r * LDW + c4 * 4]) =
            *reinterpret_cast<const float4*>(&W2b[r * H + c4 * 4]);
    }
    if (threadIdx.x < H) {
        ba[threadIdx.x] = b2a[threadIdx.x];
        bb[threadIdx.x] = b2b[threadIdx.x];
    }
    __syncthreads();

    int wave = threadIdx.x >> 6;
    int lane = threadIdx.x & 63;
    int n = blockIdx.x * 4 + wave;
    if (n >= N) return;

    float t = 0.f;
    if (lane < H) t = fmaxf(U[(size_t)n * H + lane] + ba[lane], 0.f);

    float logit = -INFINITY;
    if (lane < H) {
        float a = bb[lane];
#pragma unroll 8
        for (int k = 0; k < H; ++k) {
            float tk = __shfl(t, k);
            a = fmaf(tk, Ws[k * LDW + lane], a);
        }
        logit = a;
    }
    float m = logit;
#pragma unroll
    for (int off = 32; off; off >>= 1) m = fmaxf(m, __shfl_xor(m, off));
    float ex = (lane < H) ? expf(logit - m) : 0.f;
    float s = ex;
#pragma unroll
    for (int off = 32; off; off >>= 1) s += __shfl_xor(s, off);
    if (lane < H) out[(size_t)n * H + lane] = logit - m - logf(s);
}

// ================= launcher =================
extern "C" void kernel_launch(void* const* d_in, const int* in_sizes, int n_in,
                              void* d_out, int out_size, void* d_ws, size_t ws_size,
                              hipStream_t stream) {
    const float* x   = (const float*)d_in[0];
    const int* edges = (const int*)d_in[1];
    const float* W1a = (const float*)d_in[2];
    const float* b1a = (const float*)d_in[3];
    const float* W1b = (const float*)d_in[4];
    const float* b1b = (const float*)d_in[5];
    const float* W2a = (const float*)d_in[6];
    const float* b2a = (const float*)d_in[7];
    const float* W2b = (const float*)d_in[8];
    const float* b2b = (const float*)d_in[9];

    const int N = NNODES;
    const int E = in_sizes[1] / 2;
    const int* srcp = edges;
    const int* dstp = edges + E;

    auto au = [](size_t v) { return (v + 255) & ~(size_t)255; };
    char* p = (char*)d_ws;
    int* deg     = (int*)p; p += au((size_t)N * 4);
    int* offs    = (int*)p; p += au((size_t)(N + 1) * 4);
    int* cursor  = (int*)p; p += au((size_t)N * 4);
    int* lexcl   = (int*)p; p += au((size_t)N * 4);
    int* blksums = (int*)p; p += au((size_t)64 * 4);
    int* csr     = (int*)p; p += au((size_t)E * 4);
    float* bufA  = (float*)p; p += au((size_t)N * INC * 4);   // agg1 out; later T(fp32)+U+Tb
    float* bufB  = (float*)p; p += au((size_t)N * HIDC * 4);  // xh (bf16) then X1
    float* bufC  = (float*)p; p += au((size_t)N * HIDC * 4);  // H1

    // aliases (lifetimes disjoint):
    unsigned int* xh = (unsigned int*)bufB;                   // N*100 bf16 = 10 MB, dead before gemm1 writes bufB
    float* bufT = bufA;                                       // N x 40 fp32 (T2 self)
    float* bufU = bufA + (size_t)N * OUTC;                    // N x 40 fp32 (agg2 out)
    unsigned short* Tb = (unsigned short*)(bufA + (size_t)2 * N * OUTC);  // N*40 bf16 = 4 MB (fits bufA tail)

    const int nb = (N + 1023) / 1024;  // 49
    const int n2 = N * INC / 2;        // 2.5M uint packs

    // ---- x -> bf16 table (independent of CSR chain)
    cast_x_bf16<<<(n2 + 255) / 256, 256, 0, stream>>>((const float2*)x, xh, n2);

    // ---- CSR build
    hipMemsetAsync(deg, 0, (size_t)N * sizeof(int), stream);
    count_kernel<<<(E + 255) / 256, 256, 0, stream>>>(dstp, deg, E);
    scan_pass1<<<nb, 256, 0, stream>>>(deg, lexcl, blksums, N);
    scan_pass2<<<1, 64, 0, stream>>>(blksums, nb, offs + N);
    scan_pass3<<<(N + 255) / 256, 256, 0, stream>>>(lexcl, blksums, offs, cursor, N);
    scatter_bucket<<<NBUCKET * SCHUNKS, 256, 0, stream>>>(srcp, dstp, cursor, csr, E);

    // ---- layer 1 (bf16 neighbor gather)
    agg_wide_bf<<<(N + 7) / 8, 256, 0, stream>>>((const float4*)x, (const uint2*)xh,
                                                 offs, csr, (float4*)bufA, N);
    gemm128_v2<100, 25, true><<<(N + 63) / 64, 256, 0, stream>>>(bufA, W1a, b1a, bufB, N);
    gemm128_v2<128, 32, true><<<(N + 63) / 64, 256, 0, stream>>>(bufB, W1b, b1b, bufC, N);

    // ---- layer 2 (reassociated; bf16 gather)
    gemm_t2<<<(N + 63) / 64, 256, 0, stream>>>(bufC, W2a, bufT, Tb, N);
    agg40_bf<<<(N + 23) / 24, 256, 0, stream>>>((const float4*)bufT, (const uint2*)Tb,
                                                offs, csr, (float4*)bufU, N);
    epi40<<<(N + 3) / 4, 256, 0, stream>>>(bufU, b2a, W2b, b2b, (float*)d_out, N);
}

// Round 6
// 210.122 us; speedup vs baseline: 2.6922x; 1.3052x over previous
//
#include <hip/hip_runtime.h>

// ---------------- problem constants ----------------
#define NNODES 50000
#define INC 100
#define HIDC 128
#define OUTC 40
#define NBUCKET 8
#define BUCKET_SZ ((NNODES + NBUCKET - 1) / NBUCKET)   // 6250
#define SCHUNKS 256

typedef short bf16x8 __attribute__((ext_vector_type(8)));
typedef float f32x4 __attribute__((ext_vector_type(4)));

// bf16 helpers (RNE pack, shift unpack)
__device__ __forceinline__ unsigned short f2bf(float f) {
    unsigned int u = __float_as_uint(f);
    unsigned int r = (u + 0x7FFFu + ((u >> 16) & 1u)) >> 16;
    return (unsigned short)r;
}
__device__ __forceinline__ unsigned int pack2(float a, float b) {
    return (unsigned int)f2bf(a) | ((unsigned int)f2bf(b) << 16);
}
__device__ __forceinline__ float4 bf4(uint2 a) {
    return make_float4(__uint_as_float(a.x << 16), __uint_as_float(a.x & 0xFFFF0000u),
                       __uint_as_float(a.y << 16), __uint_as_float(a.y & 0xFFFF0000u));
}

// ================= x -> bf16 table =================
__global__ __launch_bounds__(256) void cast_x_bf16(const float2* __restrict__ x2,
                                                   unsigned int* __restrict__ xh, int n2) {
    int i = blockIdx.x * 256 + threadIdx.x;
    if (i < n2) {
        float2 v = x2[i];
        xh[i] = pack2(v.x, v.y);
    }
}

// ================= weight prep: Wt[j][128] = bf16(W[k][j]), zero-padded =================
__global__ __launch_bounds__(256) void prep_wt(const float* __restrict__ W,
                                               unsigned short* __restrict__ Wt,
                                               int K_in, int J_in, int J_out) {
    int idx = blockIdx.x * 256 + threadIdx.x;
    if (idx >= J_out * 128) return;
    int j = idx >> 7, k = idx & 127;
    float v = (j < J_in && k < K_in) ? W[k * J_in + j] : 0.f;
    Wt[idx] = f2bf(v);
}

// ================= CSR build =================
__global__ __launch_bounds__(256) void count_kernel(const int* __restrict__ dst,
                                                    int* __restrict__ deg, int E) {
    int e = blockIdx.x * 256 + threadIdx.x;
    if (e < E) atomicAdd(&deg[dst[e]], 1);
}

__global__ __launch_bounds__(256) void scan_pass1(const int* __restrict__ deg,
                                                  int* __restrict__ lexcl,
                                                  int* __restrict__ blk_sums, int n) {
    __shared__ int wsum[4];
    int base = blockIdx.x * 1024;
    int t = threadIdx.x;
    int i0 = base + t * 4;
    int a = (i0 + 0 < n) ? deg[i0 + 0] : 0;
    int b = (i0 + 1 < n) ? deg[i0 + 1] : 0;
    int c = (i0 + 2 < n) ? deg[i0 + 2] : 0;
    int d = (i0 + 3 < n) ? deg[i0 + 3] : 0;
    int s4 = a + b + c + d;
    int lane = t & 63, w = t >> 6;
    int incl = s4;
#pragma unroll
    for (int off = 1; off < 64; off <<= 1) {
        int u = __shfl_up(incl, off);
        if (lane >= off) incl += u;
    }
    if (lane == 63) wsum[w] = incl;
    __syncthreads();
    int wbase = 0;
#pragma unroll
    for (int j = 0; j < 4; ++j)
        if (j < w) wbase += wsum[j];
    int excl = wbase + incl - s4;
    if (i0 + 0 < n) lexcl[i0 + 0] = excl;
    if (i0 + 1 < n) lexcl[i0 + 1] = excl + a;
    if (i0 + 2 < n) lexcl[i0 + 2] = excl + a + b;
    if (i0 + 3 < n) lexcl[i0 + 3] = excl + a + b + c;
    if (t == 255) blk_sums[blockIdx.x] = wbase + incl;
}

__global__ __launch_bounds__(64) void scan_pass2(int* __restrict__ blk_sums, int nb,
                                                 int* __restrict__ offs_end) {
    int lane = threadIdx.x;
    int v = (lane < nb) ? blk_sums[lane] : 0;
    int incl = v;
#pragma unroll
    for (int off = 1; off < 64; off <<= 1) {
        int u = __shfl_up(incl, off);
        if (lane >= off) incl += u;
    }
    if (lane < nb) blk_sums[lane] = incl - v;
    if (lane == 63) offs_end[0] = incl;
}

__global__ __launch_bounds__(256) void scan_pass3(const int* __restrict__ lexcl,
                                                  const int* __restrict__ blk_sums,
                                                  int* __restrict__ offs,
                                                  int* __restrict__ cursor, int n) {
    int i = blockIdx.x * 256 + threadIdx.x;
    if (i < n) {
        int v = lexcl[i] + blk_sums[i >> 10];
        offs[i] = v;
        cursor[i] = v;
    }
}

// XCD-affine bucketed scatter (blockIdx%8 -> XCD -> csr region)
__global__ __launch_bounds__(256) void scatter_bucket(const int* __restrict__ src,
                                                      const int* __restrict__ dst,
                                                      int* __restrict__ cursor,
                                                      int* __restrict__ csr, int E) {
    int bucket = blockIdx.x & (NBUCKET - 1);
    int chunk = blockIdx.x >> 3;
    int lo = (int)((long long)E * chunk / SCHUNKS);
    int hi = (int)((long long)E * (chunk + 1) / SCHUNKS);
    int blo = bucket * BUCKET_SZ;
    int bhi = blo + BUCKET_SZ;
    for (int e = lo + (int)threadIdx.x; e < hi; e += 256) {
        int d = dst[e];
        if (d >= blo && d < bhi) {
            int pos = atomicAdd(&cursor[d], 1);
            csr[pos] = src[e];
        }
    }
}

// ================= layer-1 aggregation: bf16 gather, fp32 self+acc, bf16 out [N][128] padded =================
__global__ __launch_bounds__(256) void agg_wide_bf(const float4* __restrict__ self,
                                                   const uint2* __restrict__ featbf,
                                                   const int* __restrict__ offs,
                                                   const int* __restrict__ csr,
                                                   unsigned short* __restrict__ Abf, int N) {
    constexpr int C4 = 25;
    int node = blockIdx.x * 8 + (threadIdx.x >> 5);
    int l = threadIdx.x & 31;
    if (node >= N) return;
    if (l >= C4) {  // zero-pad cols 100..127
        *reinterpret_cast<uint2*>(&Abf[(size_t)node * 128 + l * 4]) = make_uint2(0u, 0u);
        return;
    }
    int s = offs[node], e = offs[node + 1];
    float4 acc = self[(size_t)node * C4 + l];
    int i = s;
    for (; i + 8 <= e; i += 8) {
        int n0 = csr[i], n1 = csr[i + 1], n2 = csr[i + 2], n3 = csr[i + 3];
        int n4 = csr[i + 4], n5 = csr[i + 5], n6 = csr[i + 6], n7 = csr[i + 7];
        float4 v0 = bf4(featbf[(size_t)n0 * C4 + l]);
        float4 v1 = bf4(featbf[(size_t)n1 * C4 + l]);
        float4 v2 = bf4(featbf[(size_t)n2 * C4 + l]);
        float4 v3 = bf4(featbf[(size_t)n3 * C4 + l]);
        float4 v4 = bf4(featbf[(size_t)n4 * C4 + l]);
        float4 v5 = bf4(featbf[(size_t)n5 * C4 + l]);
        float4 v6 = bf4(featbf[(size_t)n6 * C4 + l]);
        float4 v7 = bf4(featbf[(size_t)n7 * C4 + l]);
        acc.x += ((v0.x + v1.x) + (v2.x + v3.x)) + ((v4.x + v5.x) + (v6.x + v7.x));
        acc.y += ((v0.y + v1.y) + (v2.y + v3.y)) + ((v4.y + v5.y) + (v6.y + v7.y));
        acc.z += ((v0.z + v1.z) + (v2.z + v3.z)) + ((v4.z + v5.z) + (v6.z + v7.z));
        acc.w += ((v0.w + v1.w) + (v2.w + v3.w)) + ((v4.w + v5.w) + (v6.w + v7.w));
    }
    for (; i + 4 <= e; i += 4) {
        int n0 = csr[i], n1 = csr[i + 1], n2 = csr[i + 2], n3 = csr[i + 3];
        float4 v0 = bf4(featbf[(size_t)n0 * C4 + l]);
        float4 v1 = bf4(featbf[(size_t)n1 * C4 + l]);
        float4 v2 = bf4(featbf[(size_t)n2 * C4 + l]);
        float4 v3 = bf4(featbf[(size_t)n3 * C4 + l]);
        acc.x += (v0.x + v1.x) + (v2.x + v3.x);
        acc.y += (v0.y + v1.y) + (v2.y + v3.y);
        acc.z += (v0.z + v1.z) + (v2.z + v3.z);
        acc.w += (v0.w + v1.w) + (v2.w + v3.w);
    }
    for (; i < e; ++i) {
        int sn = csr[i];
        float4 v = bf4(featbf[(size_t)sn * C4 + l]);
        acc.x += v.x; acc.y += v.y; acc.z += v.z; acc.w += v.w;
    }
    *reinterpret_cast<uint2*>(&Abf[(size_t)node * 128 + l * 4]) =
        make_uint2(pack2(acc.x, acc.y), pack2(acc.z, acc.w));
}

// ================= MFMA GEMM: out[N,128] = relu(A[N,128]bf16 @ Wt^T + b) in bf16 =================
// BM=64, 4 waves (2x2): wave = 32 rows x 64 cols. K=128. Frags: contiguous-8 ds_read_b128;
// same per-lane k-run for A and B => result invariant to HW (g,e)->k mapping.
__global__ __launch_bounds__(256) void gemm_mfma128(const unsigned short* __restrict__ Abf,
                                                    const unsigned short* __restrict__ Wt,
                                                    const float* __restrict__ bias,
                                                    unsigned short* __restrict__ out, int N) {
    constexpr int LDW = 136;  // ushort pitch (272B, 16B-aligned)
    __shared__ unsigned short As[64 * LDW];
    __shared__ unsigned short Ws[128 * LDW];
    __shared__ float bs[128];

    const int tid = threadIdx.x;
    const int n0 = blockIdx.x * 64;

    // stage A (64 rows x 256B)
#pragma unroll
    for (int i = 0; i < 4; ++i) {
        int idx = tid + i * 256;
        int row = idx >> 4, c = idx & 15;
        int n = n0 + row;
        uint4 v = make_uint4(0u, 0u, 0u, 0u);
        if (n < N) v = *reinterpret_cast<const uint4*>(&Abf[(size_t)n * 128 + c * 8]);
        *reinterpret_cast<uint4*>(&As[row * LDW + c * 8]) = v;
    }
    // stage Wt (128 rows x 256B)
#pragma unroll
    for (int i = 0; i < 8; ++i) {
        int idx = tid + i * 256;
        int row = idx >> 4, c = idx & 15;
        uint4 v = *reinterpret_cast<const uint4*>(&Wt[(size_t)row * 128 + c * 8]);
        *reinterpret_cast<uint4*>(&Ws[row * LDW + c * 8]) = v;
    }
    if (tid < 128) bs[tid] = bias[tid];
    __syncthreads();

    const int w = tid >> 6, l = tid & 63;
    const int wr = w >> 1, wc = w & 1;
    const int r = l & 15, g = l >> 4;

    f32x4 acc[2][4];
#pragma unroll
    for (int rt = 0; rt < 2; ++rt)
#pragma unroll
        for (int ct = 0; ct < 4; ++ct) {
            float b = bs[wc * 64 + ct * 16 + r];
            acc[rt][ct] = (f32x4){b, b, b, b};
        }

#pragma unroll
    for (int s = 0; s < 4; ++s) {
        bf16x8 af[2], bfr[4];
#pragma unroll
        for (int rt = 0; rt < 2; ++rt)
            af[rt] = *reinterpret_cast<const bf16x8*>(
                &As[(wr * 32 + rt * 16 + r) * LDW + s * 32 + g * 8]);
#pragma unroll
        for (int ct = 0; ct < 4; ++ct)
            bfr[ct] = *reinterpret_cast<const bf16x8*>(
                &Ws[(wc * 64 + ct * 16 + r) * LDW + s * 32 + g * 8]);
#pragma unroll
        for (int rt = 0; rt < 2; ++rt)
#pragma unroll
            for (int ct = 0; ct < 4; ++ct)
                acc[rt][ct] = __builtin_amdgcn_mfma_f32_16x16x32_bf16(
                    af[rt], bfr[ct], acc[rt][ct], 0, 0, 0);
    }

    // D layout: row = 4*g + reg, col = r (verified)
#pragma unroll
    for (int rt = 0; rt < 2; ++rt) {
#pragma unroll
        for (int reg = 0; reg < 4; ++reg) {
            int n = n0 + wr * 32 + rt * 16 + 4 * g + reg;
            if (n < N) {
#pragma unroll
                for (int ct = 0; ct < 4; ++ct) {
                    int j = wc * 64 + ct * 16 + r;
                    float v = fmaxf(acc[rt][ct][reg], 0.f);
                    out[(size_t)n * 128 + j] = f2bf(v);
                }
            }
        }
    }
}

// ================= MFMA GEMM: Tb[N,40]bf16 = H1[N,128]bf16 @ W2a (no bias/relu) =================
// BM=64, 4 waves x 16 rows, J padded to 48 (3 col-tiles).
__global__ __launch_bounds__(256) void gemm_t2_mfma(const unsigned short* __restrict__ Abf,
                                                    const unsigned short* __restrict__ Wt,
                                                    unsigned short* __restrict__ Tb, int N) {
    constexpr int LDW = 136;
    __shared__ unsigned short As[64 * LDW];
    __shared__ unsigned short Ws[48 * LDW];

    const int tid = threadIdx.x;
    const int n0 = blockIdx.x * 64;

#pragma unroll
    for (int i = 0; i < 4; ++i) {
        int idx = tid + i * 256;
        int row = idx >> 4, c = idx & 15;
        int n = n0 + row;
        uint4 v = make_uint4(0u, 0u, 0u, 0u);
        if (n < N) v = *reinterpret_cast<const uint4*>(&Abf[(size_t)n * 128 + c * 8]);
        *reinterpret_cast<uint4*>(&As[row * LDW + c * 8]) = v;
    }
#pragma unroll
    for (int i = 0; i < 3; ++i) {
        int idx = tid + i * 256;
        int row = idx >> 4, c = idx & 15;
        uint4 v = *reinterpret_cast<const uint4*>(&Wt[(size_t)row * 128 + c * 8]);
        *reinterpret_cast<uint4*>(&Ws[row * LDW + c * 8]) = v;
    }
    __syncthreads();

    const int w = tid >> 6, l = tid & 63;
    const int r = l & 15, g = l >> 4;

    f32x4 acc[3] = {(f32x4){0,0,0,0}, (f32x4){0,0,0,0}, (f32x4){0,0,0,0}};

#pragma unroll
    for (int s = 0; s < 4; ++s) {
        bf16x8 af = *reinterpret_cast<const bf16x8*>(
            &As[(w * 16 + r) * LDW + s * 32 + g * 8]);
        bf16x8 bfr[3];
#pragma unroll
        for (int ct = 0; ct < 3; ++ct)
            bfr[ct] = *reinterpret_cast<const bf16x8*>(
                &Ws[(ct * 16 + r) * LDW + s * 32 + g * 8]);
#pragma unroll
        for (int ct = 0; ct < 3; ++ct)
            acc[ct] = __builtin_amdgcn_mfma_f32_16x16x32_bf16(af, bfr[ct], acc[ct], 0, 0, 0);
    }

#pragma unroll
    for (int reg = 0; reg < 4; ++reg) {
        int n = n0 + w * 16 + 4 * g + reg;
        if (n < N) {
#pragma unroll
            for (int ct = 0; ct < 3; ++ct) {
                int j = ct * 16 + r;
                if (j < OUTC) Tb[(size_t)n * OUTC + j] = f2bf(acc[ct][reg]);
            }
        }
    }
}

// ================= 40-dim aggregation: bf16 gather + bf16 self, fp32 acc =================
__global__ __launch_bounds__(256) void agg40_bf(const uint2* __restrict__ Tbf,
                                                const int* __restrict__ offs,
                                                const int* __restrict__ csr,
                                                float4* __restrict__ U, int N) {
    int wave = threadIdx.x >> 6;
    int lane = threadIdx.x & 63;
    int g = lane / 10;
    int sub = lane - g * 10;
    int node = blockIdx.x * 24 + wave * 6 + g;
    if (g >= 6 || node >= N) return;
    int s = offs[node], e = offs[node + 1];
    float4 acc = bf4(Tbf[(size_t)node * 10 + sub]);
    int i = s;
    for (; i + 8 <= e; i += 8) {
        int n0 = csr[i], n1 = csr[i + 1], n2 = csr[i + 2], n3 = csr[i + 3];
        int n4 = csr[i + 4], n5 = csr[i + 5], n6 = csr[i + 6], n7 = csr[i + 7];
        float4 v0 = bf4(Tbf[(size_t)n0 * 10 + sub]);
        float4 v1 = bf4(Tbf[(size_t)n1 * 10 + sub]);
        float4 v2 = bf4(Tbf[(size_t)n2 * 10 + sub]);
        float4 v3 = bf4(Tbf[(size_t)n3 * 10 + sub]);
        float4 v4 = bf4(Tbf[(size_t)n4 * 10 + sub]);
        float4 v5 = bf4(Tbf[(size_t)n5 * 10 + sub]);
        float4 v6 = bf4(Tbf[(size_t)n6 * 10 + sub]);
        float4 v7 = bf4(Tbf[(size_t)n7 * 10 + sub]);
        acc.x += ((v0.x + v1.x) + (v2.x + v3.x)) + ((v4.x + v5.x) + (v6.x + v7.x));
        acc.y += ((v0.y + v1.y) + (v2.y + v3.y)) + ((v4.y + v5.y) + (v6.y + v7.y));
        acc.z += ((v0.z + v1.z) + (v2.z + v3.z)) + ((v4.z + v5.z) + (v6.z + v7.z));
        acc.w += ((v0.w + v1.w) + (v2.w + v3.w)) + ((v4.w + v5.w) + (v6.w + v7.w));
    }
    for (; i + 4 <= e; i += 4) {
        int n0 = csr[i], n1 = csr[i + 1], n2 = csr[i + 2], n3 = csr[i + 3];
        float4 v0 = bf4(Tbf[(size_t)n0 * 10 + sub]);
        float4 v1 = bf4(Tbf[(size_t)n1 * 10 + sub]);
        float4 v2 = bf4(Tbf[(size_t)n2 * 10 + sub]);
        float4 v3 = bf4(Tbf[(size_t)n3 * 10 + sub]);
        acc.x += (v0.x + v1.x) + (v2.x + v3.x);
        acc.y += (v0.y + v1.y) + (v2.y + v3.y);
        acc.z += (v0.z + v1.z) + (v2.z + v3.z);
        acc.w += (v0.w + v1.w) + (v2.w + v3.w);
    }
    for (; i < e; ++i) {
        int sn = csr[i];
        float4 v = bf4(Tbf[(size_t)sn * 10 + sub]);
        acc.x += v.x; acc.y += v.y; acc.z += v.z; acc.w += v.w;
    }
    U[(size_t)node * 10 + sub] = acc;
}

// ================= epilogue: logits = relu(U + b2a) @ W2b + b2b ; out = log_softmax =================
__global__ __launch_bounds__(256) void epi40(const float* __restrict__ U,
                                             const float* __restrict__ b2a,
                                             const float* __restrict__ W2b,
                                             const float* __restrict__ b2b,
                                             float* __restrict__ out, int N) {
    constexpr int H = 40, LDW = 44;
    __shared__ float Ws[H * LDW];
    __shared__ float ba[H], bb[H];
    for (int idx = threadIdx.x; idx < H * (H / 4); idx += 256) {
        int r = idx / 10, c4 = idx - r * 10;
        *reinterpret_cast<float4*>(&Ws[r * LDW + c4 * 4]) =
            *reinterpret_cast<const float4*>(&W2b[r * H + c4 * 4]);
    }
    if (threadIdx.x < H) {
        ba[threadIdx.x] = b2a[threadIdx.x];
        bb[threadIdx.x] = b2b[threadIdx.x];
    }
    __syncthreads();

    int wave = threadIdx.x >> 6;
    int lane = threadIdx.x & 63;
    int n = blockIdx.x * 4 + wave;
    if (n >= N) return;

    float t = 0.f;
    if (lane < H) t = fmaxf(U[(size_t)n * H + lane] + ba[lane], 0.f);

    float logit = -INFINITY;
    if (lane < H) {
        float a = bb[lane];
#pragma unroll 8
        for (int k = 0; k < H; ++k) {
            float tk = __shfl(t, k);
            a = fmaf(tk, Ws[k * LDW + lane], a);
        }
        logit = a;
    }
    float m = logit;
#pragma unroll
    for (int off = 32; off; off >>= 1) m = fmaxf(m, __shfl_xor(m, off));
    float ex = (lane < H) ? expf(logit - m) : 0.f;
    float s = ex;
#pragma unroll
    for (int off = 32; off; off >>= 1) s += __shfl_xor(s, off);
    if (lane < H) out[(size_t)n * H + lane] = logit - m - logf(s);
}

// ================= launcher =================
extern "C" void kernel_launch(void* const* d_in, const int* in_sizes, int n_in,
                              void* d_out, int out_size, void* d_ws, size_t ws_size,
                              hipStream_t stream) {
    const float* x   = (const float*)d_in[0];
    const int* edges = (const int*)d_in[1];
    const float* W1a = (const float*)d_in[2];
    const float* b1a = (const float*)d_in[3];
    const float* W1b = (const float*)d_in[4];
    const float* b1b = (const float*)d_in[5];
    const float* W2a = (const float*)d_in[6];
    const float* b2a = (const float*)d_in[7];
    const float* W2b = (const float*)d_in[8];
    const float* b2b = (const float*)d_in[9];

    const int N = NNODES;
    const int E = in_sizes[1] / 2;
    const int* srcp = edges;
    const int* dstp = edges + E;

    auto au = [](size_t v) { return (v + 255) & ~(size_t)255; };
    char* p = (char*)d_ws;
    int* deg     = (int*)p; p += au((size_t)N * 4);
    int* offs    = (int*)p; p += au((size_t)(N + 1) * 4);
    int* cursor  = (int*)p; p += au((size_t)N * 4);
    int* lexcl   = (int*)p; p += au((size_t)N * 4);
    int* blksums = (int*)p; p += au((size_t)64 * 4);
    int* csr     = (int*)p; p += au((size_t)E * 4);
    unsigned int*   xh   = (unsigned int*)p;   p += au((size_t)N * INC * 2);       // bf16 x
    unsigned short* Abf  = (unsigned short*)p; p += au((size_t)N * 128 * 2);       // agg1 out
    unsigned short* X1bf = (unsigned short*)p; p += au((size_t)N * 128 * 2);
    unsigned short* H1bf = (unsigned short*)p; p += au((size_t)N * 128 * 2);
    unsigned short* Tb   = (unsigned short*)p; p += au((size_t)N * OUTC * 2);
    float*          bufU = (float*)p;          p += au((size_t)N * OUTC * 4);
    unsigned short* Wt1a = (unsigned short*)p; p += au((size_t)128 * 128 * 2);
    unsigned short* Wt1b = (unsigned short*)p; p += au((size_t)128 * 128 * 2);
    unsigned short* Wt2a = (unsigned short*)p; p += au((size_t)48 * 128 * 2);

    const int nb = (N + 1023) / 1024;  // 49
    const int n2 = N * INC / 2;

    // ---- prep (independent)
    cast_x_bf16<<<(n2 + 255) / 256, 256, 0, stream>>>((const float2*)x, xh, n2);
    prep_wt<<<(128 * 128 + 255) / 256, 256, 0, stream>>>(W1a, Wt1a, INC, HIDC, 128);
    prep_wt<<<(128 * 128 + 255) / 256, 256, 0, stream>>>(W1b, Wt1b, HIDC, HIDC, 128);
    prep_wt<<<(48 * 128 + 255) / 256, 256, 0, stream>>>(W2a, Wt2a, HIDC, OUTC, 48);

    // ---- CSR build
    hipMemsetAsync(deg, 0, (size_t)N * sizeof(int), stream);
    count_kernel<<<(E + 255) / 256, 256, 0, stream>>>(dstp, deg, E);
    scan_pass1<<<nb, 256, 0, stream>>>(deg, lexcl, blksums, N);
    scan_pass2<<<1, 64, 0, stream>>>(blksums, nb, offs + N);
    scan_pass3<<<(N + 255) / 256, 256, 0, stream>>>(lexcl, blksums, offs, cursor, N);
    scatter_bucket<<<NBUCKET * SCHUNKS, 256, 0, stream>>>(srcp, dstp, cursor, csr, E);

    // ---- layer 1
    agg_wide_bf<<<(N + 7) / 8, 256, 0, stream>>>((const float4*)x, (const uint2*)xh,
                                                 offs, csr, Abf, N);
    gemm_mfma128<<<(N + 63) / 64, 256, 0, stream>>>(Abf, Wt1a, b1a, X1bf, N);
    gemm_mfma128<<<(N + 63) / 64, 256, 0, stream>>>(X1bf, Wt1b, b1b, H1bf, N);

    // ---- layer 2 (reassociated)
    gemm_t2_mfma<<<(N + 63) / 64, 256, 0, stream>>>(H1bf, Wt2a, Tb, N);
    agg40_bf<<<(N + 23) / 24, 256, 0, stream>>>((const uint2*)Tb, offs, csr,
                                                (float4*)bufU, N);
    epi40<<<(N + 3) / 4, 256, 0, stream>>>(bufU, b2a, W2b, b2b, (float*)d_out, N);
}

// Round 8
// 181.875 us; speedup vs baseline: 3.1103x; 1.1553x over previous
//
#include <hip/hip_runtime.h>

// ---------------- problem constants ----------------
#define NNODES 50000
#define INC 100
#define HIDC 128
#define OUTC 40
#define NBUCKET 8
#define BUCKET_SZ ((NNODES + NBUCKET - 1) / NBUCKET)   // 6250
#define SCHUNKS 256

typedef short bf16x8 __attribute__((ext_vector_type(8)));
typedef float f32x4 __attribute__((ext_vector_type(4)));

// bf16 helpers (RNE pack, shift unpack)
__device__ __forceinline__ unsigned short f2bf(float f) {
    unsigned int u = __float_as_uint(f);
    unsigned int r = (u + 0x7FFFu + ((u >> 16) & 1u)) >> 16;
    return (unsigned short)r;
}
__device__ __forceinline__ unsigned int pack2(float a, float b) {
    return (unsigned int)f2bf(a) | ((unsigned int)f2bf(b) << 16);
}
__device__ __forceinline__ float4 bf4(uint2 a) {
    return make_float4(__uint_as_float(a.x << 16), __uint_as_float(a.x & 0xFFFF0000u),
                       __uint_as_float(a.y << 16), __uint_as_float(a.y & 0xFFFF0000u));
}

// ================= x -> bf16 table =================
__global__ __launch_bounds__(256) void cast_x_bf16(const float2* __restrict__ x2,
                                                   unsigned int* __restrict__ xh, int n2) {
    int i = blockIdx.x * 256 + threadIdx.x;
    if (i < n2) {
        float2 v = x2[i];
        xh[i] = pack2(v.x, v.y);
    }
}

// ================= weight prep: Wt[j][Kpad] = bf16(W[k][j]), zero-padded =================
__global__ __launch_bounds__(256) void prep_wt(const float* __restrict__ W,
                                               unsigned short* __restrict__ Wt,
                                               int K_in, int J_in, int J_out, int Kpad) {
    int idx = blockIdx.x * 256 + threadIdx.x;
    if (idx >= J_out * Kpad) return;
    int j = idx / Kpad, k = idx - j * Kpad;
    float v = (j < J_in && k < K_in) ? W[k * J_in + j] : 0.f;
    Wt[idx] = f2bf(v);
}

// ================= CSR build =================
__global__ __launch_bounds__(256) void count_kernel(const int* __restrict__ dst,
                                                    int* __restrict__ deg, int E) {
    int e = blockIdx.x * 256 + threadIdx.x;
    if (e < E) atomicAdd(&deg[dst[e]], 1);
}

__global__ __launch_bounds__(256) void scan_pass1(const int* __restrict__ deg,
                                                  int* __restrict__ lexcl,
                                                  int* __restrict__ blk_sums, int n) {
    __shared__ int wsum[4];
    int base = blockIdx.x * 1024;
    int t = threadIdx.x;
    int i0 = base + t * 4;
    int a = (i0 + 0 < n) ? deg[i0 + 0] : 0;
    int b = (i0 + 1 < n) ? deg[i0 + 1] : 0;
    int c = (i0 + 2 < n) ? deg[i0 + 2] : 0;
    int d = (i0 + 3 < n) ? deg[i0 + 3] : 0;
    int s4 = a + b + c + d;
    int lane = t & 63, w = t >> 6;
    int incl = s4;
#pragma unroll
    for (int off = 1; off < 64; off <<= 1) {
        int u = __shfl_up(incl, off);
        if (lane >= off) incl += u;
    }
    if (lane == 63) wsum[w] = incl;
    __syncthreads();
    int wbase = 0;
#pragma unroll
    for (int j = 0; j < 4; ++j)
        if (j < w) wbase += wsum[j];
    int excl = wbase + incl - s4;
    if (i0 + 0 < n) lexcl[i0 + 0] = excl;
    if (i0 + 1 < n) lexcl[i0 + 1] = excl + a;
    if (i0 + 2 < n) lexcl[i0 + 2] = excl + a + b;
    if (i0 + 3 < n) lexcl[i0 + 3] = excl + a + b + c;
    if (t == 255) blk_sums[blockIdx.x] = wbase + incl;
}

__global__ __launch_bounds__(64) void scan_pass2(int* __restrict__ blk_sums, int nb,
                                                 int* __restrict__ offs_end) {
    int lane = threadIdx.x;
    int v = (lane < nb) ? blk_sums[lane] : 0;
    int incl = v;
#pragma unroll
    for (int off = 1; off < 64; off <<= 1) {
        int u = __shfl_up(incl, off);
        if (lane >= off) incl += u;
    }
    if (lane < nb) blk_sums[lane] = incl - v;
    if (lane == 63) offs_end[0] = incl;
}

__global__ __launch_bounds__(256) void scan_pass3(const int* __restrict__ lexcl,
                                                  const int* __restrict__ blk_sums,
                                                  int* __restrict__ offs,
                                                  int* __restrict__ cursor, int n) {
    int i = blockIdx.x * 256 + threadIdx.x;
    if (i < n) {
        int v = lexcl[i] + blk_sums[i >> 10];
        offs[i] = v;
        cursor[i] = v;
    }
}

// XCD-affine bucketed scatter (blockIdx%8 -> XCD -> csr region)
__global__ __launch_bounds__(256) void scatter_bucket(const int* __restrict__ src,
                                                      const int* __restrict__ dst,
                                                      int* __restrict__ cursor,
                                                      int* __restrict__ csr, int E) {
    int bucket = blockIdx.x & (NBUCKET - 1);
    int chunk = blockIdx.x >> 3;
    int lo = (int)((long long)E * chunk / SCHUNKS);
    int hi = (int)((long long)E * (chunk + 1) / SCHUNKS);
    int blo = bucket * BUCKET_SZ;
    int bhi = blo + BUCKET_SZ;
    for (int e = lo + (int)threadIdx.x; e < hi; e += 256) {
        int d = dst[e];
        if (d >= blo && d < bhi) {
            int pos = atomicAdd(&cursor[d], 1);
            csr[pos] = src[e];
        }
    }
}

// ================= layer-1 aggregation: bf16 gather, fp32 self+acc, bf16 out [N][128] padded =================
__global__ __launch_bounds__(256) void agg_wide_bf(const float4* __restrict__ self,
                                                   const uint2* __restrict__ featbf,
                                                   const int* __restrict__ offs,
                                                   const int* __restrict__ csr,
                                                   unsigned short* __restrict__ Abf, int N) {
    constexpr int C4 = 25;
    int node = blockIdx.x * 8 + (threadIdx.x >> 5);
    int l = threadIdx.x & 31;
    if (node >= N) return;
    if (l >= C4) {  // zero-pad cols 100..127
        *reinterpret_cast<uint2*>(&Abf[(size_t)node * 128 + l * 4]) = make_uint2(0u, 0u);
        return;
    }
    int s = offs[node], e = offs[node + 1];
    float4 acc = self[(size_t)node * C4 + l];
    int i = s;
    for (; i + 8 <= e; i += 8) {
        int n0 = csr[i], n1 = csr[i + 1], n2 = csr[i + 2], n3 = csr[i + 3];
        int n4 = csr[i + 4], n5 = csr[i + 5], n6 = csr[i + 6], n7 = csr[i + 7];
        float4 v0 = bf4(featbf[(size_t)n0 * C4 + l]);
        float4 v1 = bf4(featbf[(size_t)n1 * C4 + l]);
        float4 v2 = bf4(featbf[(size_t)n2 * C4 + l]);
        float4 v3 = bf4(featbf[(size_t)n3 * C4 + l]);
        float4 v4 = bf4(featbf[(size_t)n4 * C4 + l]);
        float4 v5 = bf4(featbf[(size_t)n5 * C4 + l]);
        float4 v6 = bf4(featbf[(size_t)n6 * C4 + l]);
        float4 v7 = bf4(featbf[(size_t)n7 * C4 + l]);
        acc.x += ((v0.x + v1.x) + (v2.x + v3.x)) + ((v4.x + v5.x) + (v6.x + v7.x));
        acc.y += ((v0.y + v1.y) + (v2.y + v3.y)) + ((v4.y + v5.y) + (v6.y + v7.y));
        acc.z += ((v0.z + v1.z) + (v2.z + v3.z)) + ((v4.z + v5.z) + (v6.z + v7.z));
        acc.w += ((v0.w + v1.w) + (v2.w + v3.w)) + ((v4.w + v5.w) + (v6.w + v7.w));
    }
    for (; i + 4 <= e; i += 4) {
        int n0 = csr[i], n1 = csr[i + 1], n2 = csr[i + 2], n3 = csr[i + 3];
        float4 v0 = bf4(featbf[(size_t)n0 * C4 + l]);
        float4 v1 = bf4(featbf[(size_t)n1 * C4 + l]);
        float4 v2 = bf4(featbf[(size_t)n2 * C4 + l]);
        float4 v3 = bf4(featbf[(size_t)n3 * C4 + l]);
        acc.x += (v0.x + v1.x) + (v2.x + v3.x);
        acc.y += (v0.y + v1.y) + (v2.y + v3.y);
        acc.z += (v0.z + v1.z) + (v2.z + v3.z);
        acc.w += (v0.w + v1.w) + (v2.w + v3.w);
    }
    for (; i < e; ++i) {
        int sn = csr[i];
        float4 v = bf4(featbf[(size_t)sn * C4 + l]);
        acc.x += v.x; acc.y += v.y; acc.z += v.z; acc.w += v.w;
    }
    *reinterpret_cast<uint2*>(&Abf[(size_t)node * 128 + l * 4]) =
        make_uint2(pack2(acc.x, acc.y), pack2(acc.z, acc.w));
}

// ================= MFMA GEMM: out[N,128] = relu(A[N,128]bf16 @ Wt^T + b) in bf16 =================
__global__ __launch_bounds__(256) void gemm_mfma128(const unsigned short* __restrict__ Abf,
                                                    const unsigned short* __restrict__ Wt,
                                                    const float* __restrict__ bias,
                                                    unsigned short* __restrict__ out, int N) {
    constexpr int LDW = 136;  // ushort pitch (272B, 16B-aligned)
    __shared__ unsigned short As[64 * LDW];
    __shared__ unsigned short Ws[128 * LDW];
    __shared__ float bs[128];

    const int tid = threadIdx.x;
    const int n0 = blockIdx.x * 64;

#pragma unroll
    for (int i = 0; i < 4; ++i) {
        int idx = tid + i * 256;
        int row = idx >> 4, c = idx & 15;
        int n = n0 + row;
        uint4 v = make_uint4(0u, 0u, 0u, 0u);
        if (n < N) v = *reinterpret_cast<const uint4*>(&Abf[(size_t)n * 128 + c * 8]);
        *reinterpret_cast<uint4*>(&As[row * LDW + c * 8]) = v;
    }
#pragma unroll
    for (int i = 0; i < 8; ++i) {
        int idx = tid + i * 256;
        int row = idx >> 4, c = idx & 15;
        uint4 v = *reinterpret_cast<const uint4*>(&Wt[(size_t)row * 128 + c * 8]);
        *reinterpret_cast<uint4*>(&Ws[row * LDW + c * 8]) = v;
    }
    if (tid < 128) bs[tid] = bias[tid];
    __syncthreads();

    const int w = tid >> 6, l = tid & 63;
    const int wr = w >> 1, wc = w & 1;
    const int r = l & 15, g = l >> 4;

    f32x4 acc[2][4];
#pragma unroll
    for (int rt = 0; rt < 2; ++rt)
#pragma unroll
        for (int ct = 0; ct < 4; ++ct) {
            float b = bs[wc * 64 + ct * 16 + r];
            acc[rt][ct] = (f32x4){b, b, b, b};
        }

#pragma unroll
    for (int s = 0; s < 4; ++s) {
        bf16x8 af[2], bfr[4];
#pragma unroll
        for (int rt = 0; rt < 2; ++rt)
            af[rt] = *reinterpret_cast<const bf16x8*>(
                &As[(wr * 32 + rt * 16 + r) * LDW + s * 32 + g * 8]);
#pragma unroll
        for (int ct = 0; ct < 4; ++ct)
            bfr[ct] = *reinterpret_cast<const bf16x8*>(
                &Ws[(wc * 64 + ct * 16 + r) * LDW + s * 32 + g * 8]);
#pragma unroll
        for (int rt = 0; rt < 2; ++rt)
#pragma unroll
            for (int ct = 0; ct < 4; ++ct)
                acc[rt][ct] = __builtin_amdgcn_mfma_f32_16x16x32_bf16(
                    af[rt], bfr[ct], acc[rt][ct], 0, 0, 0);
    }

#pragma unroll
    for (int rt = 0; rt < 2; ++rt) {
#pragma unroll
        for (int reg = 0; reg < 4; ++reg) {
            int n = n0 + wr * 32 + rt * 16 + 4 * g + reg;
            if (n < N) {
#pragma unroll
                for (int ct = 0; ct < 4; ++ct) {
                    int j = wc * 64 + ct * 16 + r;
                    float v = fmaxf(acc[rt][ct][reg], 0.f);
                    out[(size_t)n * 128 + j] = f2bf(v);
                }
            }
        }
    }
}

// ================= MFMA GEMM: Tb[N,40]bf16 = H1[N,128]bf16 @ W2a (no bias/relu) =================
__global__ __launch_bounds__(256) void gemm_t2_mfma(const unsigned short* __restrict__ Abf,
                                                    const unsigned short* __restrict__ Wt,
                                                    unsigned short* __restrict__ Tb, int N) {
    constexpr int LDW = 136;
    __shared__ unsigned short As[64 * LDW];
    __shared__ unsigned short Ws[48 * LDW];

    const int tid = threadIdx.x;
    const int n0 = blockIdx.x * 64;

#pragma unroll
    for (int i = 0; i < 4; ++i) {
        int idx = tid + i * 256;
        int row = idx >> 4, c = idx & 15;
        int n = n0 + row;
        uint4 v = make_uint4(0u, 0u, 0u, 0u);
        if (n < N) v = *reinterpret_cast<const uint4*>(&Abf[(size_t)n * 128 + c * 8]);
        *reinterpret_cast<uint4*>(&As[row * LDW + c * 8]) = v;
    }
#pragma unroll
    for (int i = 0; i < 3; ++i) {
        int idx = tid + i * 256;
        int row = idx >> 4, c = idx & 15;
        uint4 v = *reinterpret_cast<const uint4*>(&Wt[(size_t)row * 128 + c * 8]);
        *reinterpret_cast<uint4*>(&Ws[row * LDW + c * 8]) = v;
    }
    __syncthreads();

    const int w = tid >> 6, l = tid & 63;
    const int r = l & 15, g = l >> 4;

    f32x4 acc[3] = {(f32x4){0,0,0,0}, (f32x4){0,0,0,0}, (f32x4){0,0,0,0}};

#pragma unroll
    for (int s = 0; s < 4; ++s) {
        bf16x8 af = *reinterpret_cast<const bf16x8*>(
            &As[(w * 16 + r) * LDW + s * 32 + g * 8]);
        bf16x8 bfr[3];
#pragma unroll
        for (int ct = 0; ct < 3; ++ct)
            bfr[ct] = *reinterpret_cast<const bf16x8*>(
                &Ws[(ct * 16 + r) * LDW + s * 32 + g * 8]);
#pragma unroll
        for (int ct = 0; ct < 3; ++ct)
            acc[ct] = __builtin_amdgcn_mfma_f32_16x16x32_bf16(af, bfr[ct], acc[ct], 0, 0, 0);
    }

#pragma unroll
    for (int reg = 0; reg < 4; ++reg) {
        int n = n0 + w * 16 + 4 * g + reg;
        if (n < N) {
#pragma unroll
            for (int ct = 0; ct < 3; ++ct) {
                int j = ct * 16 + r;
                if (j < OUTC) Tb[(size_t)n * OUTC + j] = f2bf(acc[ct][reg]);
            }
        }
    }
}

// ================= 40-dim aggregation: bf16 gather + bf16 self, fp32 acc =================
__global__ __launch_bounds__(256) void agg40_bf(const uint2* __restrict__ Tbf,
                                                const int* __restrict__ offs,
                                                const int* __restrict__ csr,
                                                float4* __restrict__ U, int N) {
    int wave = threadIdx.x >> 6;
    int lane = threadIdx.x & 63;
    int g = lane / 10;
    int sub = lane - g * 10;
    int node = blockIdx.x * 24 + wave * 6 + g;
    if (g >= 6 || node >= N) return;
    int s = offs[node], e = offs[node + 1];
    float4 acc = bf4(Tbf[(size_t)node * 10 + sub]);
    int i = s;
    for (; i + 8 <= e; i += 8) {
        int n0 = csr[i], n1 = csr[i + 1], n2 = csr[i + 2], n3 = csr[i + 3];
        int n4 = csr[i + 4], n5 = csr[i + 5], n6 = csr[i + 6], n7 = csr[i + 7];
        float4 v0 = bf4(Tbf[(size_t)n0 * 10 + sub]);
        float4 v1 = bf4(Tbf[(size_t)n1 * 10 + sub]);
        float4 v2 = bf4(Tbf[(size_t)n2 * 10 + sub]);
        float4 v3 = bf4(Tbf[(size_t)n3 * 10 + sub]);
        float4 v4 = bf4(Tbf[(size_t)n4 * 10 + sub]);
        float4 v5 = bf4(Tbf[(size_t)n5 * 10 + sub]);
        float4 v6 = bf4(Tbf[(size_t)n6 * 10 + sub]);
        float4 v7 = bf4(Tbf[(size_t)n7 * 10 + sub]);
        acc.x += ((v0.x + v1.x) + (v2.x + v3.x)) + ((v4.x + v5.x) + (v6.x + v7.x));
        acc.y += ((v0.y + v1.y) + (v2.y + v3.y)) + ((v4.y + v5.y) + (v6.y + v7.y));
        acc.z += ((v0.z + v1.z) + (v2.z + v3.z)) + ((v4.z + v5.z) + (v6.z + v7.z));
        acc.w += ((v0.w + v1.w) + (v2.w + v3.w)) + ((v4.w + v5.w) + (v6.w + v7.w));
    }
    for (; i + 4 <= e; i += 4) {
        int n0 = csr[i], n1 = csr[i + 1], n2 = csr[i + 2], n3 = csr[i + 3];
        float4 v0 = bf4(Tbf[(size_t)n0 * 10 + sub]);
        float4 v1 = bf4(Tbf[(size_t)n1 * 10 + sub]);
        float4 v2 = bf4(Tbf[(size_t)n2 * 10 + sub]);
        float4 v3 = bf4(Tbf[(size_t)n3 * 10 + sub]);
        acc.x += (v0.x + v1.x) + (v2.x + v3.x);
        acc.y += (v0.y + v1.y) + (v2.y + v3.y);
        acc.z += (v0.z + v1.z) + (v2.z + v3.z);
        acc.w += (v0.w + v1.w) + (v2.w + v3.w);
    }
    for (; i < e; ++i) {
        int sn = csr[i];
        float4 v = bf4(Tbf[(size_t)sn * 10 + sub]);
        acc.x += v.x; acc.y += v.y; acc.z += v.z; acc.w += v.w;
    }
    U[(size_t)node * 10 + sub] = acc;
}

// ================= MFMA epilogue: logits = relu(U+b2a)bf16 @ W2b + b2b ; log_softmax =================
// BM=64, 4 waves x 16 rows; K padded 40->64, J padded 40->48 (3 col-tiles).
__global__ __launch_bounds__(256) void epi40_mfma(const float* __restrict__ U,
                                                  const float* __restrict__ b2a,
                                                  const unsigned short* __restrict__ Wt2b,
                                                  const float* __restrict__ b2b,
                                                  float* __restrict__ out, int N) {
    constexpr int LDW = 72;  // ushort pitch (144B, 16B-aligned)
    __shared__ unsigned short As[64 * LDW];
    __shared__ unsigned short Ws[48 * LDW];
    __shared__ float ba[40], bb[40];

    const int tid = threadIdx.x;
    const int n0 = blockIdx.x * 64;

    if (tid < 40) { ba[tid] = b2a[tid]; bb[tid] = b2b[tid]; }
    // stage Wt2b: 48 rows x 8 slots of 8 bf16 = 384 uint4 loads (256 threads -> loop!)
    for (int idx = tid; idx < 384; idx += 256) {
        int row = idx >> 3, c = idx & 7;
        uint4 v = *reinterpret_cast<const uint4*>(&Wt2b[row * 64 + c * 8]);
        *reinterpret_cast<uint4*>(&Ws[row * LDW + c * 8]) = v;
    }
    __syncthreads();

    // stage A = bf16(relu(U + b2a)), cols 40..63 zero
    for (int idx = tid; idx < 64 * 8; idx += 256) {
        int row = idx >> 3, c8 = idx & 7;
        int n = n0 + row;
        uint4 o = make_uint4(0u, 0u, 0u, 0u);
        if (c8 < 5 && n < N) {
            int j = c8 * 8;
            float4 u0 = *reinterpret_cast<const float4*>(&U[(size_t)n * 40 + j]);
            float4 u1 = *reinterpret_cast<const float4*>(&U[(size_t)n * 40 + j + 4]);
            float t0 = fmaxf(u0.x + ba[j + 0], 0.f);
            float t1 = fmaxf(u0.y + ba[j + 1], 0.f);
            float t2 = fmaxf(u0.z + ba[j + 2], 0.f);
            float t3 = fmaxf(u0.w + ba[j + 3], 0.f);
            float t4 = fmaxf(u1.x + ba[j + 4], 0.f);
            float t5 = fmaxf(u1.y + ba[j + 5], 0.f);
            float t6 = fmaxf(u1.z + ba[j + 6], 0.f);
            float t7 = fmaxf(u1.w + ba[j + 7], 0.f);
            o = make_uint4(pack2(t0, t1), pack2(t2, t3), pack2(t4, t5), pack2(t6, t7));
        }
        *reinterpret_cast<uint4*>(&As[row * LDW + c8 * 8]) = o;
    }
    __syncthreads();

    const int w = tid >> 6, l = tid & 63;
    const int r = l & 15, g = l >> 4;

    f32x4 acc[3] = {(f32x4){0,0,0,0}, (f32x4){0,0,0,0}, (f32x4){0,0,0,0}};
#pragma unroll
    for (int s = 0; s < 2; ++s) {
        bf16x8 af = *reinterpret_cast<const bf16x8*>(
            &As[(w * 16 + r) * LDW + s * 32 + g * 8]);
#pragma unroll
        for (int ct = 0; ct < 3; ++ct) {
            bf16x8 bfr = *reinterpret_cast<const bf16x8*>(
                &Ws[(ct * 16 + r) * LDW + s * 32 + g * 8]);
            acc[ct] = __builtin_amdgcn_mfma_f32_16x16x32_bf16(af, bfr, acc[ct], 0, 0, 0);
        }
    }

    // D layout: row = w*16 + 4*g + reg, col = ct*16 + r. Row reduce across the 16-lane r-group.
    float bb0 = bb[r], bb1 = bb[16 + r], bb2 = (r < 8) ? bb[32 + r] : 0.f;
#pragma unroll
    for (int reg = 0; reg < 4; ++reg) {
        int n = n0 + w * 16 + 4 * g + reg;
        float lg0 = acc[0][reg] + bb0;
        float lg1 = acc[1][reg] + bb1;
        float lg2 = (r < 8) ? acc[2][reg] + bb2 : -INFINITY;
        float m = fmaxf(fmaxf(lg0, lg1), lg2);
#pragma unroll
        for (int off = 1; off < 16; off <<= 1) m = fmaxf(m, __shfl_xor(m, off));
        float s = expf(lg0 - m) + expf(lg1 - m) + ((r < 8) ? expf(lg2 - m) : 0.f);
#pragma unroll
        for (int off = 1; off < 16; off <<= 1) s += __shfl_xor(s, off);
        float lse = m + logf(s);
        if (n < N) {
            out[(size_t)n * OUTC + r] = lg0 - lse;
            out[(size_t)n * OUTC + 16 + r] = lg1 - lse;
            if (r < 8) out[(size_t)n * OUTC + 32 + r] = lg2 - lse;
        }
    }
}

// ================= launcher =================
extern "C" void kernel_launch(void* const* d_in, const int* in_sizes, int n_in,
                              void* d_out, int out_size, void* d_ws, size_t ws_size,
                              hipStream_t stream) {
    const float* x   = (const float*)d_in[0];
    const int* edges = (const int*)d_in[1];
    const float* W1a = (const float*)d_in[2];
    const float* b1a = (const float*)d_in[3];
    const float* W1b = (const float*)d_in[4];
    const float* b1b = (const float*)d_in[5];
    const float* W2a = (const float*)d_in[6];
    const float* b2a = (const float*)d_in[7];
    const float* W2b = (const float*)d_in[8];
    const float* b2b = (const float*)d_in[9];

    const int N = NNODES;
    const int E = in_sizes[1] / 2;
    const int* srcp = edges;
    const int* dstp = edges + E;

    auto au = [](size_t v) { return (v + 255) & ~(size_t)255; };
    char* p = (char*)d_ws;
    int* deg     = (int*)p; p += au((size_t)N * 4);
    int* offs    = (int*)p; p += au((size_t)(N + 1) * 4);
    int* cursor  = (int*)p; p += au((size_t)N * 4);
    int* lexcl   = (int*)p; p += au((size_t)N * 4);
    int* blksums = (int*)p; p += au((size_t)64 * 4);
    int* csr     = (int*)p; p += au((size_t)E * 4);
    unsigned int*   xh   = (unsigned int*)p;   p += au((size_t)N * INC * 2);
    unsigned short* Abf  = (unsigned short*)p; p += au((size_t)N * 128 * 2);
    unsigned short* X1bf = (unsigned short*)p; p += au((size_t)N * 128 * 2);
    unsigned short* H1bf = (unsigned short*)p; p += au((size_t)N * 128 * 2);
    unsigned short* Tb   = (unsigned short*)p; p += au((size_t)N * OUTC * 2);
    float*          bufU = (float*)p;          p += au((size_t)N * OUTC * 4);
    unsigned short* Wt1a = (unsigned short*)p; p += au((size_t)128 * 128 * 2);
    unsigned short* Wt1b = (unsigned short*)p; p += au((size_t)128 * 128 * 2);
    unsigned short* Wt2a = (unsigned short*)p; p += au((size_t)48 * 128 * 2);
    unsigned short* Wt2b = (unsigned short*)p; p += au((size_t)48 * 64 * 2);

    const int nb = (N + 1023) / 1024;  // 49
    const int n2 = N * INC / 2;

    // ---- prep (independent)
    cast_x_bf16<<<(n2 + 255) / 256, 256, 0, stream>>>((const float2*)x, xh, n2);
    prep_wt<<<(128 * 128 + 255) / 256, 256, 0, stream>>>(W1a, Wt1a, INC, HIDC, 128, 128);
    prep_wt<<<(128 * 128 + 255) / 256, 256, 0, stream>>>(W1b, Wt1b, HIDC, HIDC, 128, 128);
    prep_wt<<<(48 * 128 + 255) / 256, 256, 0, stream>>>(W2a, Wt2a, HIDC, OUTC, 48, 128);
    prep_wt<<<(48 * 64 + 255) / 256, 256, 0, stream>>>(W2b, Wt2b, OUTC, OUTC, 48, 64);

    // ---- CSR build
    hipMemsetAsync(deg, 0, (size_t)N * sizeof(int), stream);
    count_kernel<<<(E + 255) / 256, 256, 0, stream>>>(dstp, deg, E);
    scan_pass1<<<nb, 256, 0, stream>>>(deg, lexcl, blksums, N);
    scan_pass2<<<1, 64, 0, stream>>>(blksums, nb, offs + N);
    scan_pass3<<<(N + 255) / 256, 256, 0, stream>>>(lexcl, blksums, offs, cursor, N);
    scatter_bucket<<<NBUCKET * SCHUNKS, 256, 0, stream>>>(srcp, dstp, cursor, csr, E);

    // ---- layer 1
    agg_wide_bf<<<(N + 7) / 8, 256, 0, stream>>>((const float4*)x, (const uint2*)xh,
                                                 offs, csr, Abf, N);
    gemm_mfma128<<<(N + 63) / 64, 256, 0, stream>>>(Abf, Wt1a, b1a, X1bf, N);
    gemm_mfma128<<<(N + 63) / 64, 256, 0, stream>>>(X1bf, Wt1b, b1b, H1bf, N);

    // ---- layer 2 (reassociated)
    gemm_t2_mfma<<<(N + 63) / 64, 256, 0, stream>>>(H1bf, Wt2a, Tb, N);
    agg40_bf<<<(N + 23) / 24, 256, 0, stream>>>((const uint2*)Tb, offs, csr,
                                                (float4*)bufU, N);
    epi40_mfma<<<(N + 63) / 64, 256, 0, stream>>>(bufU, b2a, Wt2b, b2b, (float*)d_out, N);
}

// Round 9
// 180.947 us; speedup vs baseline: 3.1263x; 1.0051x over previous
//
#include <hip/hip_runtime.h>

// ---------------- problem constants ----------------
#define NNODES 50000
#define INC 100
#define HIDC 128
#define OUTC 40
#define NBUCKET 8
#define BUCKET_SZ ((NNODES + NBUCKET - 1) / NBUCKET)   // 6250
#define SCHUNKS 256

typedef short bf16x8 __attribute__((ext_vector_type(8)));
typedef float f32x4 __attribute__((ext_vector_type(4)));

// bf16 helpers (RNE pack, shift unpack)
__device__ __forceinline__ unsigned short f2bf(float f) {
    unsigned int u = __float_as_uint(f);
    unsigned int r = (u + 0x7FFFu + ((u >> 16) & 1u)) >> 16;
    return (unsigned short)r;
}
__device__ __forceinline__ unsigned int pack2(float a, float b) {
    return (unsigned int)f2bf(a) | ((unsigned int)f2bf(b) << 16);
}
__device__ __forceinline__ float4 bf4(uint2 a) {
    return make_float4(__uint_as_float(a.x << 16), __uint_as_float(a.x & 0xFFFF0000u),
                       __uint_as_float(a.y << 16), __uint_as_float(a.y & 0xFFFF0000u));
}

// ================= fused prep: x->bf16 + 4 weight transposes =================
__global__ __launch_bounds__(256) void prep_all(const float2* __restrict__ x2,
                                                unsigned int* __restrict__ xh, int n2,
                                                const float* __restrict__ W1a,
                                                unsigned short* __restrict__ Wt1a,
                                                const float* __restrict__ W1b,
                                                unsigned short* __restrict__ Wt1b,
                                                const float* __restrict__ W2a,
                                                unsigned short* __restrict__ Wt2a,
                                                const float* __restrict__ W2b,
                                                unsigned short* __restrict__ Wt2b) {
    int i = blockIdx.x * 256 + threadIdx.x;
    if (i < n2) {
        float2 v = x2[i];
        xh[i] = pack2(v.x, v.y);
        return;
    }
    i -= n2;
    if (i < 128 * 128) {  // Wt1a[j][128], W1a is [100][128]
        int j = i >> 7, k = i & 127;
        Wt1a[i] = f2bf((k < INC) ? W1a[k * HIDC + j] : 0.f);
        return;
    }
    i -= 128 * 128;
    if (i < 128 * 128) {  // Wt1b[j][128], W1b is [128][128]
        int j = i >> 7, k = i & 127;
        Wt1b[i] = f2bf(W1b[k * HIDC + j]);
        return;
    }
    i -= 128 * 128;
    if (i < 48 * 128) {  // Wt2a[j][128], W2a is [128][40]
        int j = i >> 7, k = i & 127;
        Wt2a[i] = f2bf((j < OUTC) ? W2a[k * OUTC + j] : 0.f);
        return;
    }
    i -= 48 * 128;
    if (i < 48 * 64) {  // Wt2b[j][64], W2b is [40][40]
        int j = i >> 6, k = i & 63;
        Wt2b[i] = f2bf((j < OUTC && k < OUTC) ? W2b[k * OUTC + j] : 0.f);
        return;
    }
}

// ================= CSR build =================
__global__ __launch_bounds__(256) void count_kernel(const int* __restrict__ dst,
                                                    int* __restrict__ deg, int E) {
    int e = blockIdx.x * 256 + threadIdx.x;
    if (e < E) atomicAdd(&deg[__builtin_nontemporal_load(&dst[e])], 1);
}

__global__ __launch_bounds__(256) void scan_pass1(const int* __restrict__ deg,
                                                  int* __restrict__ lexcl,
                                                  int* __restrict__ blk_sums, int n) {
    __shared__ int wsum[4];
    int base = blockIdx.x * 1024;
    int t = threadIdx.x;
    int i0 = base + t * 4;
    int a = (i0 + 0 < n) ? deg[i0 + 0] : 0;
    int b = (i0 + 1 < n) ? deg[i0 + 1] : 0;
    int c = (i0 + 2 < n) ? deg[i0 + 2] : 0;
    int d = (i0 + 3 < n) ? deg[i0 + 3] : 0;
    int s4 = a + b + c + d;
    int lane = t & 63, w = t >> 6;
    int incl = s4;
#pragma unroll
    for (int off = 1; off < 64; off <<= 1) {
        int u = __shfl_up(incl, off);
        if (lane >= off) incl += u;
    }
    if (lane == 63) wsum[w] = incl;
    __syncthreads();
    int wbase = 0;
#pragma unroll
    for (int j = 0; j < 4; ++j)
        if (j < w) wbase += wsum[j];
    int excl = wbase + incl - s4;
    if (i0 + 0 < n) lexcl[i0 + 0] = excl;
    if (i0 + 1 < n) lexcl[i0 + 1] = excl + a;
    if (i0 + 2 < n) lexcl[i0 + 2] = excl + a + b;
    if (i0 + 3 < n) lexcl[i0 + 3] = excl + a + b + c;
    if (t == 255) blk_sums[blockIdx.x] = wbase + incl;
}

__global__ __launch_bounds__(64) void scan_pass2(int* __restrict__ blk_sums, int nb,
                                                 int* __restrict__ offs_end) {
    int lane = threadIdx.x;
    int v = (lane < nb) ? blk_sums[lane] : 0;
    int incl = v;
#pragma unroll
    for (int off = 1; off < 64; off <<= 1) {
        int u = __shfl_up(incl, off);
        if (lane >= off) incl += u;
    }
    if (lane < nb) blk_sums[lane] = incl - v;
    if (lane == 63) offs_end[0] = incl;
}

__global__ __launch_bounds__(256) void scan_pass3(const int* __restrict__ lexcl,
                                                  const int* __restrict__ blk_sums,
                                                  int* __restrict__ offs,
                                                  int* __restrict__ cursor, int n) {
    int i = blockIdx.x * 256 + threadIdx.x;
    if (i < n) {
        int v = lexcl[i] + blk_sums[i >> 10];
        offs[i] = v;
        cursor[i] = v;
    }
}

// XCD-affine bucketed scatter (blockIdx%8 -> XCD -> csr region).
// Non-temporal dst/src reads: the 3.2 MB/pass edge stream must not evict the
// bucket's dirty partial csr lines from the XCD's L2 (that eviction was the
// 9x write amplification -> HBM RMW).
__global__ __launch_bounds__(256) void scatter_bucket(const int* __restrict__ src,
                                                      const int* __restrict__ dst,
                                                      int* __restrict__ cursor,
                                                      int* __restrict__ csr, int E) {
    int bucket = blockIdx.x & (NBUCKET - 1);
    int chunk = blockIdx.x >> 3;
    int lo = (int)((long long)E * chunk / SCHUNKS);
    int hi = (int)((long long)E * (chunk + 1) / SCHUNKS);
    int blo = bucket * BUCKET_SZ;
    int bhi = blo + BUCKET_SZ;
    for (int e = lo + (int)threadIdx.x; e < hi; e += 256) {
        int d = __builtin_nontemporal_load(&dst[e]);
        if (d >= blo && d < bhi) {
            int sv = __builtin_nontemporal_load(&src[e]);
            int pos = atomicAdd(&cursor[d], 1);
            csr[pos] = sv;
        }
    }
}

// ================= layer-1 aggregation: bf16 gather, fp32 self+acc, bf16 out [N][128] padded =================
__global__ __launch_bounds__(256) void agg_wide_bf(const float4* __restrict__ self,
                                                   const uint2* __restrict__ featbf,
                                                   const int* __restrict__ offs,
                                                   const int* __restrict__ csr,
                                                   unsigned short* __restrict__ Abf, int N) {
    constexpr int C4 = 25;
    int node = blockIdx.x * 8 + (threadIdx.x >> 5);
    int l = threadIdx.x & 31;
    if (node >= N) return;
    if (l >= C4) {  // zero-pad cols 100..127
        *reinterpret_cast<uint2*>(&Abf[(size_t)node * 128 + l * 4]) = make_uint2(0u, 0u);
        return;
    }
    int s = offs[node], e = offs[node + 1];
    float4 acc = self[(size_t)node * C4 + l];
    int i = s;
    for (; i + 8 <= e; i += 8) {
        int n0 = __builtin_nontemporal_load(&csr[i + 0]);
        int n1 = __builtin_nontemporal_load(&csr[i + 1]);
        int n2 = __builtin_nontemporal_load(&csr[i + 2]);
        int n3 = __builtin_nontemporal_load(&csr[i + 3]);
        int n4 = __builtin_nontemporal_load(&csr[i + 4]);
        int n5 = __builtin_nontemporal_load(&csr[i + 5]);
        int n6 = __builtin_nontemporal_load(&csr[i + 6]);
        int n7 = __builtin_nontemporal_load(&csr[i + 7]);
        float4 v0 = bf4(featbf[(size_t)n0 * C4 + l]);
        float4 v1 = bf4(featbf[(size_t)n1 * C4 + l]);
        float4 v2 = bf4(featbf[(size_t)n2 * C4 + l]);
        float4 v3 = bf4(featbf[(size_t)n3 * C4 + l]);
        float4 v4 = bf4(featbf[(size_t)n4 * C4 + l]);
        float4 v5 = bf4(featbf[(size_t)n5 * C4 + l]);
        float4 v6 = bf4(featbf[(size_t)n6 * C4 + l]);
        float4 v7 = bf4(featbf[(size_t)n7 * C4 + l]);
        acc.x += ((v0.x + v1.x) + (v2.x + v3.x)) + ((v4.x + v5.x) + (v6.x + v7.x));
        acc.y += ((v0.y + v1.y) + (v2.y + v3.y)) + ((v4.y + v5.y) + (v6.y + v7.y));
        acc.z += ((v0.z + v1.z) + (v2.z + v3.z)) + ((v4.z + v5.z) + (v6.z + v7.z));
        acc.w += ((v0.w + v1.w) + (v2.w + v3.w)) + ((v4.w + v5.w) + (v6.w + v7.w));
    }
    for (; i + 4 <= e; i += 4) {
        int n0 = __builtin_nontemporal_load(&csr[i + 0]);
        int n1 = __builtin_nontemporal_load(&csr[i + 1]);
        int n2 = __builtin_nontemporal_load(&csr[i + 2]);
        int n3 = __builtin_nontemporal_load(&csr[i + 3]);
        float4 v0 = bf4(featbf[(size_t)n0 * C4 + l]);
        float4 v1 = bf4(featbf[(size_t)n1 * C4 + l]);
        float4 v2 = bf4(featbf[(size_t)n2 * C4 + l]);
        float4 v3 = bf4(featbf[(size_t)n3 * C4 + l]);
        acc.x += (v0.x + v1.x) + (v2.x + v3.x);
        acc.y += (v0.y + v1.y) + (v2.y + v3.y);
        acc.z += (v0.z + v1.z) + (v2.z + v3.z);
        acc.w += (v0.w + v1.w) + (v2.w + v3.w);
    }
    for (; i < e; ++i) {
        int sn = __builtin_nontemporal_load(&csr[i]);
        float4 v = bf4(featbf[(size_t)sn * C4 + l]);
        acc.x += v.x; acc.y += v.y; acc.z += v.z; acc.w += v.w;
    }
    *reinterpret_cast<uint2*>(&Abf[(size_t)node * 128 + l * 4]) =
        make_uint2(pack2(acc.x, acc.y), pack2(acc.z, acc.w));
}

// ================= MFMA GEMM: out[N,128] = relu(A[N,128]bf16 @ Wt^T + b) in bf16 =================
__global__ __launch_bounds__(256) void gemm_mfma128(const unsigned short* __restrict__ Abf,
                                                    const unsigned short* __restrict__ Wt,
                                                    const float* __restrict__ bias,
                                                    unsigned short* __restrict__ out, int N) {
    constexpr int LDW = 136;  // ushort pitch (272B, 16B-aligned)
    __shared__ unsigned short As[64 * LDW];
    __shared__ unsigned short Ws[128 * LDW];
    __shared__ float bs[128];

    const int tid = threadIdx.x;
    const int n0 = blockIdx.x * 64;

#pragma unroll
    for (int i = 0; i < 4; ++i) {
        int idx = tid + i * 256;
        int row = idx >> 4, c = idx & 15;
        int n = n0 + row;
        uint4 v = make_uint4(0u, 0u, 0u, 0u);
        if (n < N) v = *reinterpret_cast<const uint4*>(&Abf[(size_t)n * 128 + c * 8]);
        *reinterpret_cast<uint4*>(&As[row * LDW + c * 8]) = v;
    }
#pragma unroll
    for (int i = 0; i < 8; ++i) {
        int idx = tid + i * 256;
        int row = idx >> 4, c = idx & 15;
        uint4 v = *reinterpret_cast<const uint4*>(&Wt[(size_t)row * 128 + c * 8]);
        *reinterpret_cast<uint4*>(&Ws[row * LDW + c * 8]) = v;
    }
    if (tid < 128) bs[tid] = bias[tid];
    __syncthreads();

    const int w = tid >> 6, l = tid & 63;
    const int wr = w >> 1, wc = w & 1;
    const int r = l & 15, g = l >> 4;

    f32x4 acc[2][4];
#pragma unroll
    for (int rt = 0; rt < 2; ++rt)
#pragma unroll
        for (int ct = 0; ct < 4; ++ct) {
            float b = bs[wc * 64 + ct * 16 + r];
            acc[rt][ct] = (f32x4){b, b, b, b};
        }

#pragma unroll
    for (int s = 0; s < 4; ++s) {
        bf16x8 af[2], bfr[4];
#pragma unroll
        for (int rt = 0; rt < 2; ++rt)
            af[rt] = *reinterpret_cast<const bf16x8*>(
                &As[(wr * 32 + rt * 16 + r) * LDW + s * 32 + g * 8]);
#pragma unroll
        for (int ct = 0; ct < 4; ++ct)
            bfr[ct] = *reinterpret_cast<const bf16x8*>(
                &Ws[(wc * 64 + ct * 16 + r) * LDW + s * 32 + g * 8]);
#pragma unroll
        for (int rt = 0; rt < 2; ++rt)
#pragma unroll
            for (int ct = 0; ct < 4; ++ct)
                acc[rt][ct] = __builtin_amdgcn_mfma_f32_16x16x32_bf16(
                    af[rt], bfr[ct], acc[rt][ct], 0, 0, 0);
    }

#pragma unroll
    for (int rt = 0; rt < 2; ++rt) {
#pragma unroll
        for (int reg = 0; reg < 4; ++reg) {
            int n = n0 + wr * 32 + rt * 16 + 4 * g + reg;
            if (n < N) {
#pragma unroll
                for (int ct = 0; ct < 4; ++ct) {
                    int j = wc * 64 + ct * 16 + r;
                    float v = fmaxf(acc[rt][ct][reg], 0.f);
                    out[(size_t)n * 128 + j] = f2bf(v);
                }
            }
        }
    }
}

// ================= MFMA GEMM: Tb[N,40]bf16 = H1[N,128]bf16 @ W2a (no bias/relu) =================
__global__ __launch_bounds__(256) void gemm_t2_mfma(const unsigned short* __restrict__ Abf,
                                                    const unsigned short* __restrict__ Wt,
                                                    unsigned short* __restrict__ Tb, int N) {
    constexpr int LDW = 136;
    __shared__ unsigned short As[64 * LDW];
    __shared__ unsigned short Ws[48 * LDW];

    const int tid = threadIdx.x;
    const int n0 = blockIdx.x * 64;

#pragma unroll
    for (int i = 0; i < 4; ++i) {
        int idx = tid + i * 256;
        int row = idx >> 4, c = idx & 15;
        int n = n0 + row;
        uint4 v = make_uint4(0u, 0u, 0u, 0u);
        if (n < N) v = *reinterpret_cast<const uint4*>(&Abf[(size_t)n * 128 + c * 8]);
        *reinterpret_cast<uint4*>(&As[row * LDW + c * 8]) = v;
    }
#pragma unroll
    for (int i = 0; i < 3; ++i) {
        int idx = tid + i * 256;
        int row = idx >> 4, c = idx & 15;
        uint4 v = *reinterpret_cast<const uint4*>(&Wt[(size_t)row * 128 + c * 8]);
        *reinterpret_cast<uint4*>(&Ws[row * LDW + c * 8]) = v;
    }
    __syncthreads();

    const int w = tid >> 6, l = tid & 63;
    const int r = l & 15, g = l >> 4;

    f32x4 acc[3] = {(f32x4){0,0,0,0}, (f32x4){0,0,0,0}, (f32x4){0,0,0,0}};

#pragma unroll
    for (int s = 0; s < 4; ++s) {
        bf16x8 af = *reinterpret_cast<const bf16x8*>(
            &As[(w * 16 + r) * LDW + s * 32 + g * 8]);
        bf16x8 bfr[3];
#pragma unroll
        for (int ct = 0; ct < 3; ++ct)
            bfr[ct] = *reinterpret_cast<const bf16x8*>(
                &Ws[(ct * 16 + r) * LDW + s * 32 + g * 8]);
#pragma unroll
        for (int ct = 0; ct < 3; ++ct)
            acc[ct] = __builtin_amdgcn_mfma_f32_16x16x32_bf16(af, bfr[ct], acc[ct], 0, 0, 0);
    }

#pragma unroll
    for (int reg = 0; reg < 4; ++reg) {
        int n = n0 + w * 16 + 4 * g + reg;
        if (n < N) {
#pragma unroll
            for (int ct = 0; ct < 3; ++ct) {
                int j = ct * 16 + r;
                if (j < OUTC) Tb[(size_t)n * OUTC + j] = f2bf(acc[ct][reg]);
            }
        }
    }
}

// ================= 40-dim aggregation: bf16 gather + bf16 self, fp32 acc =================
__global__ __launch_bounds__(256) void agg40_bf(const uint2* __restrict__ Tbf,
                                                const int* __restrict__ offs,
                                                const int* __restrict__ csr,
                                                float4* __restrict__ U, int N) {
    int wave = threadIdx.x >> 6;
    int lane = threadIdx.x & 63;
    int g = lane / 10;
    int sub = lane - g * 10;
    int node = blockIdx.x * 24 + wave * 6 + g;
    if (g >= 6 || node >= N) return;
    int s = offs[node], e = offs[node + 1];
    float4 acc = bf4(Tbf[(size_t)node * 10 + sub]);
    int i = s;
    for (; i + 8 <= e; i += 8) {
        int n0 = __builtin_nontemporal_load(&csr[i + 0]);
        int n1 = __builtin_nontemporal_load(&csr[i + 1]);
        int n2 = __builtin_nontemporal_load(&csr[i + 2]);
        int n3 = __builtin_nontemporal_load(&csr[i + 3]);
        int n4 = __builtin_nontemporal_load(&csr[i + 4]);
        int n5 = __builtin_nontemporal_load(&csr[i + 5]);
        int n6 = __builtin_nontemporal_load(&csr[i + 6]);
        int n7 = __builtin_nontemporal_load(&csr[i + 7]);
        float4 v0 = bf4(Tbf[(size_t)n0 * 10 + sub]);
        float4 v1 = bf4(Tbf[(size_t)n1 * 10 + sub]);
        float4 v2 = bf4(Tbf[(size_t)n2 * 10 + sub]);
        float4 v3 = bf4(Tbf[(size_t)n3 * 10 + sub]);
        float4 v4 = bf4(Tbf[(size_t)n4 * 10 + sub]);
        float4 v5 = bf4(Tbf[(size_t)n5 * 10 + sub]);
        float4 v6 = bf4(Tbf[(size_t)n6 * 10 + sub]);
        float4 v7 = bf4(Tbf[(size_t)n7 * 10 + sub]);
        acc.x += ((v0.x + v1.x) + (v2.x + v3.x)) + ((v4.x + v5.x) + (v6.x + v7.x));
        acc.y += ((v0.y + v1.y) + (v2.y + v3.y)) + ((v4.y + v5.y) + (v6.y + v7.y));
        acc.z += ((v0.z + v1.z) + (v2.z + v3.z)) + ((v4.z + v5.z) + (v6.z + v7.z));
        acc.w += ((v0.w + v1.w) + (v2.w + v3.w)) + ((v4.w + v5.w) + (v6.w + v7.w));
    }
    for (; i + 4 <= e; i += 4) {
        int n0 = __builtin_nontemporal_load(&csr[i + 0]);
        int n1 = __builtin_nontemporal_load(&csr[i + 1]);
        int n2 = __builtin_nontemporal_load(&csr[i + 2]);
        int n3 = __builtin_nontemporal_load(&csr[i + 3]);
        float4 v0 = bf4(Tbf[(size_t)n0 * 10 + sub]);
        float4 v1 = bf4(Tbf[(size_t)n1 * 10 + sub]);
        float4 v2 = bf4(Tbf[(size_t)n2 * 10 + sub]);
        float4 v3 = bf4(Tbf[(size_t)n3 * 10 + sub]);
        acc.x += (v0.x + v1.x) + (v2.x + v3.x);
        acc.y += (v0.y + v1.y) + (v2.y + v3.y);
        acc.z += (v0.z + v1.z) + (v2.z + v3.z);
        acc.w += (v0.w + v1.w) + (v2.w + v3.w);
    }
    for (; i < e; ++i) {
        int sn = __builtin_nontemporal_load(&csr[i]);
        float4 v = bf4(Tbf[(size_t)sn * 10 + sub]);
        acc.x += v.x; acc.y += v.y; acc.z += v.z; acc.w += v.w;
    }
    U[(size_t)node * 10 + sub] = acc;
}

// ================= MFMA epilogue: logits = relu(U+b2a)bf16 @ W2b + b2b ; log_softmax =================
__global__ __launch_bounds__(256) void epi40_mfma(const float* __restrict__ U,
                                                  const float* __restrict__ b2a,
                                                  const unsigned short* __restrict__ Wt2b,
                                                  const float* __restrict__ b2b,
                                                  float* __restrict__ out, int N) {
    constexpr int LDW = 72;  // ushort pitch (144B, 16B-aligned)
    __shared__ unsigned short As[64 * LDW];
    __shared__ unsigned short Ws[48 * LDW];
    __shared__ float ba[40], bb[40];

    const int tid = threadIdx.x;
    const int n0 = blockIdx.x * 64;

    if (tid < 40) { ba[tid] = b2a[tid]; bb[tid] = b2b[tid]; }
    for (int idx = tid; idx < 384; idx += 256) {
        int row = idx >> 3, c = idx & 7;
        uint4 v = *reinterpret_cast<const uint4*>(&Wt2b[row * 64 + c * 8]);
        *reinterpret_cast<uint4*>(&Ws[row * LDW + c * 8]) = v;
    }
    __syncthreads();

    // stage A = bf16(relu(U + b2a)), cols 40..63 zero
    for (int idx = tid; idx < 64 * 8; idx += 256) {
        int row = idx >> 3, c8 = idx & 7;
        int n = n0 + row;
        uint4 o = make_uint4(0u, 0u, 0u, 0u);
        if (c8 < 5 && n < N) {
            int j = c8 * 8;
            float4 u0 = *reinterpret_cast<const float4*>(&U[(size_t)n * 40 + j]);
            float4 u1 = *reinterpret_cast<const float4*>(&U[(size_t)n * 40 + j + 4]);
            float t0 = fmaxf(u0.x + ba[j + 0], 0.f);
            float t1 = fmaxf(u0.y + ba[j + 1], 0.f);
            float t2 = fmaxf(u0.z + ba[j + 2], 0.f);
            float t3 = fmaxf(u0.w + ba[j + 3], 0.f);
            float t4 = fmaxf(u1.x + ba[j + 4], 0.f);
            float t5 = fmaxf(u1.y + ba[j + 5], 0.f);
            float t6 = fmaxf(u1.z + ba[j + 6], 0.f);
            float t7 = fmaxf(u1.w + ba[j + 7], 0.f);
            o = make_uint4(pack2(t0, t1), pack2(t2, t3), pack2(t4, t5), pack2(t6, t7));
        }
        *reinterpret_cast<uint4*>(&As[row * LDW + c8 * 8]) = o;
    }
    __syncthreads();

    const int w = tid >> 6, l = tid & 63;
    const int r = l & 15, g = l >> 4;

    f32x4 acc[3] = {(f32x4){0,0,0,0}, (f32x4){0,0,0,0}, (f32x4){0,0,0,0}};
#pragma unroll
    for (int s = 0; s < 2; ++s) {
        bf16x8 af = *reinterpret_cast<const bf16x8*>(
            &As[(w * 16 + r) * LDW + s * 32 + g * 8]);
#pragma unroll
        for (int ct = 0; ct < 3; ++ct) {
            bf16x8 bfr = *reinterpret_cast<const bf16x8*>(
                &Ws[(ct * 16 + r) * LDW + s * 32 + g * 8]);
            acc[ct] = __builtin_amdgcn_mfma_f32_16x16x32_bf16(af, bfr, acc[ct], 0, 0, 0);
        }
    }

    // D layout: row = w*16 + 4*g + reg, col = ct*16 + r. Row reduce across the 16-lane r-group.
    float bb0 = bb[r], bb1 = bb[16 + r], bb2 = (r < 8) ? bb[32 + r] : 0.f;
#pragma unroll
    for (int reg = 0; reg < 4; ++reg) {
        int n = n0 + w * 16 + 4 * g + reg;
        float lg0 = acc[0][reg] + bb0;
        float lg1 = acc[1][reg] + bb1;
        float lg2 = (r < 8) ? acc[2][reg] + bb2 : -INFINITY;
        float m = fmaxf(fmaxf(lg0, lg1), lg2);
#pragma unroll
        for (int off = 1; off < 16; off <<= 1) m = fmaxf(m, __shfl_xor(m, off));
        float s = expf(lg0 - m) + expf(lg1 - m) + ((r < 8) ? expf(lg2 - m) : 0.f);
#pragma unroll
        for (int off = 1; off < 16; off <<= 1) s += __shfl_xor(s, off);
        float lse = m + logf(s);
        if (n < N) {
            out[(size_t)n * OUTC + r] = lg0 - lse;
            out[(size_t)n * OUTC + 16 + r] = lg1 - lse;
            if (r < 8) out[(size_t)n * OUTC + 32 + r] = lg2 - lse;
        }
    }
}

// ================= launcher =================
extern "C" void kernel_launch(void* const* d_in, const int* in_sizes, int n_in,
                              void* d_out, int out_size, void* d_ws, size_t ws_size,
                              hipStream_t stream) {
    const float* x   = (const float*)d_in[0];
    const int* edges = (const int*)d_in[1];
    const float* W1a = (const float*)d_in[2];
    const float* b1a = (const float*)d_in[3];
    const float* W1b = (const float*)d_in[4];
    const float* b1b = (const float*)d_in[5];
    const float* W2a = (const float*)d_in[6];
    const float* b2a = (const float*)d_in[7];
    const float* W2b = (const float*)d_in[8];
    const float* b2b = (const float*)d_in[9];

    const int N = NNODES;
    const int E = in_sizes[1] / 2;
    const int* srcp = edges;
    const int* dstp = edges + E;

    auto au = [](size_t v) { return (v + 255) & ~(size_t)255; };
    char* p = (char*)d_ws;
    int* deg     = (int*)p; p += au((size_t)N * 4);
    int* offs    = (int*)p; p += au((size_t)(N + 1) * 4);
    int* cursor  = (int*)p; p += au((size_t)N * 4);
    int* lexcl   = (int*)p; p += au((size_t)N * 4);
    int* blksums = (int*)p; p += au((size_t)64 * 4);
    int* csr     = (int*)p; p += au((size_t)E * 4);
    unsigned int*   xh   = (unsigned int*)p;   p += au((size_t)N * INC * 2);
    unsigned short* Abf  = (unsigned short*)p; p += au((size_t)N * 128 * 2);
    unsigned short* X1bf = (unsigned short*)p; p += au((size_t)N * 128 * 2);
    unsigned short* H1bf = (unsigned short*)p; p += au((size_t)N * 128 * 2);
    unsigned short* Tb   = (unsigned short*)p; p += au((size_t)N * OUTC * 2);
    float*          bufU = (float*)p;          p += au((size_t)N * OUTC * 4);
    unsigned short* Wt1a = (unsigned short*)p; p += au((size_t)128 * 128 * 2);
    unsigned short* Wt1b = (unsigned short*)p; p += au((size_t)128 * 128 * 2);
    unsigned short* Wt2a = (unsigned short*)p; p += au((size_t)48 * 128 * 2);
    unsigned short* Wt2b = (unsigned short*)p; p += au((size_t)48 * 64 * 2);

    const int nb = (N + 1023) / 1024;  // 49
    const int n2 = N * INC / 2;
    const int prep_total = n2 + 128 * 128 + 128 * 128 + 48 * 128 + 48 * 64;

    // ---- fused prep (independent of CSR chain)
    prep_all<<<(prep_total + 255) / 256, 256, 0, stream>>>(
        (const float2*)x, xh, n2, W1a, Wt1a, W1b, Wt1b, W2a, Wt2a, W2b, Wt2b);

    // ---- CSR build
    hipMemsetAsync(deg, 0, (size_t)N * sizeof(int), stream);
    count_kernel<<<(E + 255) / 256, 256, 0, stream>>>(dstp, deg, E);
    scan_pass1<<<nb, 256, 0, stream>>>(deg, lexcl, blksums, N);
    scan_pass2<<<1, 64, 0, stream>>>(blksums, nb, offs + N);
    scan_pass3<<<(N + 255) / 256, 256, 0, stream>>>(lexcl, blksums, offs, cursor, N);
    scatter_bucket<<<NBUCKET * SCHUNKS, 256, 0, stream>>>(srcp, dstp, cursor, csr, E);

    // ---- layer 1
    agg_wide_bf<<<(N + 7) / 8, 256, 0, stream>>>((const float4*)x, (const uint2*)xh,
                                                 offs, csr, Abf, N);
    gemm_mfma128<<<(N + 63) / 64, 256, 0, stream>>>(Abf, Wt1a, b1a, X1bf, N);
    gemm_mfma128<<<(N + 63) / 64, 256, 0, stream>>>(X1bf, Wt1b, b1b, H1bf, N);

    // ---- layer 2 (reassociated)
    gemm_t2_mfma<<<(N + 63) / 64, 256, 0, stream>>>(H1bf, Wt2a, Tb, N);
    agg40_bf<<<(N + 23) / 24, 256, 0, stream>>>((const uint2*)Tb, offs, csr,
                                                (float4*)bufU, N);
    epi40_mfma<<<(N + 63) / 64, 256, 0, stream>>>(bufU, b2a, Wt2b, b2b, (float*)d_out, N);
}